// Round 5
// baseline (264.546 us; speedup 1.0000x reference)
//
#include <hip/hip_runtime.h>

typedef unsigned int u32;
typedef unsigned short u16;

static __device__ __forceinline__ float leaky(float v) {
    return v >= 0.0f ? v : 0.01f * v;
}

#define P1_CHUNK 4096
#define P1_T 256
#define NBK 512            // buckets = dst>>8  (requires nN <= 131072)
#define P2_T 256
#define SPLIT 4            // sub-blocks per bucket for agg/cnt kernels
#define SBLK 1024

// ================= pass 1: bucket histogram (bin-major gh) =================
__global__ void k_p1hist(const int* __restrict__ dst, int* __restrict__ gh,
                         int nE, int nb) {
    __shared__ int hist[NBK];
    int t = threadIdx.x;
    hist[t] = 0; hist[t + 256] = 0;
    __syncthreads();
    int base = blockIdx.x * P1_CHUNK;
    int lim = min(P1_CHUNK, nE - base);
    if (lim == P1_CHUNK) {
        const int4* p = (const int4*)(dst + base);
        for (int i = t; i < P1_CHUNK / 4; i += P1_T) {
            int4 v = p[i];
            atomicAdd(&hist[v.x >> 8], 1);
            atomicAdd(&hist[v.y >> 8], 1);
            atomicAdd(&hist[v.z >> 8], 1);
            atomicAdd(&hist[v.w >> 8], 1);
        }
    } else {
        for (int i = t; i < lim; i += P1_T)
            atomicAdd(&hist[dst[base + i] >> 8], 1);
    }
    __syncthreads();
    gh[t * nb + blockIdx.x] = hist[t];
    gh[(t + 256) * nb + blockIdx.x] = hist[t + 256];
}

// ================= generic scan (exclusive), in-place safe =================
__global__ void g_scanA(const int* __restrict__ in, int* __restrict__ out,
                        int* __restrict__ bsum, int n) {
    __shared__ int s[SBLK];
    int t = threadIdx.x, i = blockIdx.x * SBLK + t;
    int v = (i < n) ? in[i] : 0;
    s[t] = v;
    for (int o = 1; o < SBLK; o <<= 1) {
        __syncthreads();
        int x = (t >= o) ? s[t - o] : 0;
        __syncthreads();
        s[t] += x;
    }
    __syncthreads();
    if (i < n) out[i] = s[t] - v;
    if (t == SBLK - 1) bsum[blockIdx.x] = s[t];
}
__global__ void g_scanB(int* __restrict__ bsum, int nb) {
    __shared__ int s[SBLK];
    int t = threadIdx.x;
    int v = (t < nb) ? bsum[t] : 0;
    s[t] = v;
    for (int o = 1; o < SBLK; o <<= 1) {
        __syncthreads();
        int x = (t >= o) ? s[t - o] : 0;
        __syncthreads();
        s[t] += x;
    }
    __syncthreads();
    if (t < nb) bsum[t] = s[t] - v;
}
__global__ void g_scanC(int* __restrict__ out, const int* __restrict__ bsum,
                        int n, int total) {
    int i = blockIdx.x * blockDim.x + threadIdx.x;
    if (i < n) out[i] += bsum[i / SBLK];
    if (i == 0) out[n] = total;           // sentinel gh[ghN] = nE
}

// ====== pass 1 scatter: single edge pass, counts from scanned gh diffs =====
__global__ void k_p1scatter(const int* __restrict__ src, const int* __restrict__ dst,
                            const int* __restrict__ gh, u32* __restrict__ bkt,
                            int nE, int nb) {
    __shared__ int cur[NBK];
    __shared__ int loff[NBK];
    __shared__ int gb[NBK];
    __shared__ int sc[NBK];
    __shared__ u32 pay[P1_CHUNK];
    __shared__ u16 bb[P1_CHUNK];
    int t = threadIdx.x;
    int blk = blockIdx.x;
    int idx0 = t * nb + blk;
    int idx1 = (t + 256) * nb + blk;
    int g0 = gh[idx0], c0 = gh[idx0 + 1] - g0;
    int g1 = gh[idx1], c1 = gh[idx1 + 1] - g1;
    gb[t] = g0; gb[t + 256] = g1;
    sc[t] = c0; sc[t + 256] = c1;
    for (int o = 1; o < NBK; o <<= 1) {
        __syncthreads();
        int a0 = (t >= o) ? sc[t - o] : 0;
        int a1 = (t + 256 >= o) ? sc[t + 256 - o] : 0;
        __syncthreads();
        sc[t] += a0; sc[t + 256] += a1;
    }
    __syncthreads();
    loff[t] = sc[t] - c0;           loff[t + 256] = sc[t + 256] - c1;
    cur[t] = loff[t];               cur[t + 256] = loff[t + 256];
    __syncthreads();
    int base = blk * P1_CHUNK;
    int lim = min(P1_CHUNK, nE - base);
    for (int i = t; i < lim; i += P1_T) {
        int d = dst[base + i], s = src[base + i];
        int b = d >> 8;
        int r = atomicAdd(&cur[b], 1);
        pay[r] = (u32)(((d & 255) << 17) | s);
        bb[r] = (u16)b;
    }
    __syncthreads();
    for (int i = t; i < lim; i += P1_T) {
        int b = bb[i];
        bkt[gb[b] + (i - loff[b])] = pay[i];
    }
}

// ====== per-(bucket,split) bin histogram -> partial counts ================
__global__ void k_cnt(const u32* __restrict__ bkt, const int* __restrict__ gh,
                      int* __restrict__ pcnt, int nE, int nb) {
    __shared__ int h[256];
    int t = threadIdx.x;
    int blk = blockIdx.x, b = blk / SPLIT, s = blk % SPLIT;
    int base = gh[b * nb];
    int end = (b + 1 < NBK) ? gh[(b + 1) * nb] : nE;
    int sz = end - base;
    int chunk = (sz + SPLIT - 1) / SPLIT;
    int st = min(base + s * chunk, end);
    int en = min(st + chunk, end);
    h[t] = 0;
    __syncthreads();
    int a0 = min((st + 3) & ~3, en);
    if (st + t < a0) atomicAdd(&h[bkt[st + t] >> 17], 1);
    int vend = a0 + ((en - a0) & ~3);
    for (int i = a0 + t * 4; i < vend; i += P2_T * 4) {
        uint4 v = *(const uint4*)&bkt[i];
        atomicAdd(&h[v.x >> 17], 1);
        atomicAdd(&h[v.y >> 17], 1);
        atomicAdd(&h[v.z >> 17], 1);
        atomicAdd(&h[v.w >> 17], 1);
    }
    if (vend + t < en) atomicAdd(&h[bkt[vend + t] >> 17], 1);
    __syncthreads();
    pcnt[blk * 256 + t] = h[t];
}

// ====== node tables: deg -> dinv, hd0 = emb[x]*dinv ========================
__global__ void k_node(const int* __restrict__ pcnt, const int* __restrict__ x,
                       const float* __restrict__ emb, float* __restrict__ dinv,
                       float4* __restrict__ hd0, int nN) {
    int d = blockIdx.x * blockDim.x + threadIdx.x;
    if (d >= nN) return;
    int b = d >> 8, bin = d & 255;
    int deg = 0;
#pragma unroll
    for (int s = 0; s < SPLIT; ++s)
        deg += pcnt[(b * SPLIT + s) * 256 + bin];
    float di = rsqrtf((float)deg + 1.0f);
    dinv[d] = di;
    int xi = x[d] * 3;
    hd0[d] = make_float4(emb[xi] * di, emb[xi + 1] * di, emb[xi + 2] * di, 0.f);
}

// ====== agg: stream bucket sub-range, LDS fp32 bins, write partials ========
__global__ void k_agg(const u32* __restrict__ bkt, const int* __restrict__ gh,
                      const float4* __restrict__ tab, float* __restrict__ pacc,
                      int nE, int nb) {
    __shared__ float acc[3][256];
    int t = threadIdx.x;
    int blk = blockIdx.x, b = blk / SPLIT, s = blk % SPLIT;
    int base = gh[b * nb];
    int end = (b + 1 < NBK) ? gh[(b + 1) * nb] : nE;
    int sz = end - base;
    int chunk = (sz + SPLIT - 1) / SPLIT;
    int st = min(base + s * chunk, end);
    int en = min(st + chunk, end);
    acc[0][t] = 0.f; acc[1][t] = 0.f; acc[2][t] = 0.f;
    __syncthreads();
    int a0 = min((st + 3) & ~3, en);
    if (st + t < a0) {
        u32 v = bkt[st + t];
        float4 h = tab[v & 0x1FFFFu];
        int bin = v >> 17;
        atomicAdd(&acc[0][bin], h.x);
        atomicAdd(&acc[1][bin], h.y);
        atomicAdd(&acc[2][bin], h.z);
    }
    int vend = a0 + ((en - a0) & ~3);
    for (int i = a0 + t * 4; i < vend; i += P2_T * 4) {
        uint4 v = *(const uint4*)&bkt[i];
        float4 h0 = tab[v.x & 0x1FFFFu];
        float4 h1 = tab[v.y & 0x1FFFFu];
        float4 h2 = tab[v.z & 0x1FFFFu];
        float4 h3 = tab[v.w & 0x1FFFFu];
        int b0 = v.x >> 17, b1 = v.y >> 17, b2 = v.z >> 17, b3 = v.w >> 17;
        atomicAdd(&acc[0][b0], h0.x); atomicAdd(&acc[1][b0], h0.y); atomicAdd(&acc[2][b0], h0.z);
        atomicAdd(&acc[0][b1], h1.x); atomicAdd(&acc[1][b1], h1.y); atomicAdd(&acc[2][b1], h1.z);
        atomicAdd(&acc[0][b2], h2.x); atomicAdd(&acc[1][b2], h2.y); atomicAdd(&acc[2][b2], h2.z);
        atomicAdd(&acc[0][b3], h3.x); atomicAdd(&acc[1][b3], h3.y); atomicAdd(&acc[2][b3], h3.z);
    }
    if (vend + t < en) {
        u32 v = bkt[vend + t];
        float4 h = tab[v & 0x1FFFFu];
        int bin = v >> 17;
        atomicAdd(&acc[0][bin], h.x);
        atomicAdd(&acc[1][bin], h.y);
        atomicAdd(&acc[2][bin], h.z);
    }
    __syncthreads();
    float* p = pacc + (size_t)blk * 768;
    p[t] = acc[0][t]; p[256 + t] = acc[1][t]; p[512 + t] = acc[2][t];
}

// ====== fin1: combine partials + self, chain @W1->leaky->@W2, *dinv ========
__global__ void k_fin1(const float* __restrict__ pacc, const float* __restrict__ dinv,
                       const float4* __restrict__ hd0,
                       const float* __restrict__ W1, const float* __restrict__ b1,
                       const float* __restrict__ W2,
                       float4* __restrict__ hd2, int nN) {
    int d = blockIdx.x * blockDim.x + threadIdx.x;
    if (d >= nN) return;
    int b = d >> 8, bin = d & 255;
    float s0 = 0.f, s1 = 0.f, s2 = 0.f;
#pragma unroll
    for (int s = 0; s < SPLIT; ++s) {
        const float* p = pacc + (size_t)(b * SPLIT + s) * 768 + bin;
        s0 += p[0]; s1 += p[256]; s2 += p[512];
    }
    float di = dinv[d];
    float4 self = hd0[d];
    float a0 = di * (s0 + self.x);
    float a1 = di * (s1 + self.y);
    float a2 = di * (s2 + self.z);
    float o0 = 0.f, o1 = 0.f, o2 = 0.f;
#pragma unroll
    for (int k = 0; k < 16; ++k) {
        float p = leaky(a0 * W1[k] + a1 * W1[16 + k] + a2 * W1[32 + k] + b1[k]);
        o0 += p * W2[k * 3 + 0];
        o1 += p * W2[k * 3 + 1];
        o2 += p * W2[k * 3 + 2];
    }
    hd2[d] = make_float4(o0 * di, o1 * di, o2 * di, 0.f);
}

// ====== fin2: combine partials + self, h2 = leaky(di*sum + b2) =============
__global__ void k_fin2(const float* __restrict__ pacc, const float* __restrict__ dinv,
                       const float4* __restrict__ hd2, const float* __restrict__ b2,
                       float4* __restrict__ h2, int nN) {
    int d = blockIdx.x * blockDim.x + threadIdx.x;
    if (d >= nN) return;
    int b = d >> 8, bin = d & 255;
    float s0 = 0.f, s1 = 0.f, s2 = 0.f;
#pragma unroll
    for (int s = 0; s < SPLIT; ++s) {
        const float* p = pacc + (size_t)(b * SPLIT + s) * 768 + bin;
        s0 += p[0]; s1 += p[256]; s2 += p[512];
    }
    float di = dinv[d];
    float4 self = hd2[d];
    h2[d] = make_float4(leaky(di * (s0 + self.x) + b2[0]),
                        leaky(di * (s1 + self.y) + b2[1]),
                        leaky(di * (s2 + self.z) + b2[2]), 0.f);
}

// ================= per-match MLP =================
__global__ void k_mlp4(const int* __restrict__ home, const int* __restrict__ away,
                       const float4* __restrict__ h2,
                       const float* __restrict__ lw1, const float* __restrict__ lb1,
                       const float* __restrict__ lw2, const float* __restrict__ lb2,
                       const float* __restrict__ lw3, const float* __restrict__ lb3,
                       float* __restrict__ out, int nM) {
    __shared__ float s[235];
    int t = threadIdx.x;
    if (t < 96)       s[t] = lw1[t];
    else if (t < 112) s[t] = lb1[t - 96];
    else if (t < 208) s[t] = lw2[t - 112];
    else if (t < 214) s[t] = lb2[t - 208];
    else if (t < 232) s[t] = lw3[t - 214];
    else if (t < 235) s[t] = lb3[t - 232];
    __syncthreads();
    const float* sw1 = s;        const float* sb1 = s + 96;
    const float* sw2 = s + 112;  const float* sb2 = s + 208;
    const float* sw3 = s + 214;  const float* sb3 = s + 232;

    int m = blockIdx.x * blockDim.x + threadIdx.x;
    if (m >= nM) return;
    float4 zh = h2[home[m]];
    float4 za = h2[away[m]];
    float z[6] = {zh.x, zh.y, zh.z, za.x, za.y, za.z};

    float t1[16];
#pragma unroll
    for (int k = 0; k < 16; ++k) {
        float p = sb1[k];
#pragma unroll
        for (int j = 0; j < 6; ++j) p += z[j] * sw1[j * 16 + k];
        t1[k] = leaky(p);
    }
    float t2[6];
#pragma unroll
    for (int k = 0; k < 6; ++k) {
        float p = sb2[k];
#pragma unroll
        for (int j = 0; j < 16; ++j) p += t1[j] * sw2[j * 6 + k];
        t2[k] = leaky(p);
    }
#pragma unroll
    for (int k = 0; k < 3; ++k) {
        float p = sb3[k];
#pragma unroll
        for (int j = 0; j < 6; ++j) p += t2[j] * sw3[j * 3 + k];
        out[m * 3 + k] = leaky(p);
    }
}

// ================= fallback: atomic CSR build ===============
__global__ void k_hist(const int* __restrict__ dst, int* __restrict__ cnt, int nE) {
    int e = blockIdx.x * blockDim.x + threadIdx.x;
    if (e < nE) atomicAdd(&cnt[dst[e]], 1);
}
__global__ void k_prep(const int* __restrict__ off, const int* __restrict__ cnt,
                       float* __restrict__ dinv, int* __restrict__ cur, int nN) {
    int i = blockIdx.x * blockDim.x + threadIdx.x;
    if (i >= nN) return;
    dinv[i] = rsqrtf((float)cnt[i] + 1.0f);
    cur[i] = off[i];
}
__global__ void k_hd0(const int* __restrict__ x, const float* __restrict__ emb,
                      const float* __restrict__ dinv, float4* __restrict__ hd0, int nN) {
    int i = blockIdx.x * blockDim.x + threadIdx.x;
    if (i >= nN) return;
    float di = dinv[i];
    int xi = x[i] * 3;
    hd0[i] = make_float4(emb[xi] * di, emb[xi + 1] * di, emb[xi + 2] * di, 0.0f);
}
__global__ void k_place(const int* __restrict__ src, const int* __restrict__ dst,
                        int* __restrict__ cur, int* __restrict__ csr, int nE) {
    int e = blockIdx.x * blockDim.x + threadIdx.x;
    if (e >= nE) return;
    int p = atomicAdd(&cur[dst[e]], 1);
    csr[p] = src[e];
}
__global__ void k_gather1w(const int* __restrict__ off, const int* __restrict__ csr,
                           const float4* __restrict__ hd0, const float* __restrict__ dinv,
                           const float* __restrict__ W1, const float* __restrict__ b1,
                           const float* __restrict__ W2,
                           float4* __restrict__ hd2, int nN) {
    int g = blockIdx.x * blockDim.x + threadIdx.x;
    int d = g >> 6, lane = threadIdx.x & 63;
    if (d >= nN) return;
    int e0 = off[d], e1 = off[d + 1];
    float sx = 0.f, sy = 0.f, sz = 0.f;
    for (int e = e0 + lane; e < e1; e += 64) {
        float4 v = hd0[csr[e]];
        sx += v.x; sy += v.y; sz += v.z;
    }
    for (int o = 32; o; o >>= 1) {
        sx += __shfl_down(sx, o);
        sy += __shfl_down(sy, o);
        sz += __shfl_down(sz, o);
    }
    if (lane == 0) {
        float di = dinv[d];
        float4 self = hd0[d];
        float a0 = di * (sx + self.x);
        float a1 = di * (sy + self.y);
        float a2 = di * (sz + self.z);
        float o0 = 0.f, o1 = 0.f, o2 = 0.f;
#pragma unroll
        for (int k = 0; k < 16; ++k) {
            float p = leaky(a0 * W1[k] + a1 * W1[16 + k] + a2 * W1[32 + k] + b1[k]);
            o0 += p * W2[k * 3 + 0];
            o1 += p * W2[k * 3 + 1];
            o2 += p * W2[k * 3 + 2];
        }
        hd2[d] = make_float4(o0 * di, o1 * di, o2 * di, 0.0f);
    }
}
__global__ void k_gather2(const int* __restrict__ off, const int* __restrict__ csr,
                          const float4* __restrict__ hd2, const float* __restrict__ dinv,
                          const float* __restrict__ b2,
                          float4* __restrict__ h2, int nN) {
    int g = blockIdx.x * blockDim.x + threadIdx.x;
    int d = g >> 4, lane = threadIdx.x & 15;
    if (d >= nN) return;
    int e0 = off[d], e1 = off[d + 1];
    float s0 = 0.f, s1 = 0.f, s2 = 0.f;
    for (int e = e0 + lane; e < e1; e += 16) {
        float4 v = hd2[csr[e]];
        s0 += v.x; s1 += v.y; s2 += v.z;
    }
    for (int o = 8; o; o >>= 1) {
        s0 += __shfl_down(s0, o, 16);
        s1 += __shfl_down(s1, o, 16);
        s2 += __shfl_down(s2, o, 16);
    }
    if (lane == 0) {
        float di = dinv[d];
        float4 self = hd2[d];
        h2[d] = make_float4(leaky(di * (s0 + self.x) + b2[0]),
                            leaky(di * (s1 + self.y) + b2[1]),
                            leaky(di * (s2 + self.z) + b2[2]), 0.f);
    }
}

// ================= launch =================
extern "C" void kernel_launch(void* const* d_in, const int* in_sizes, int n_in,
                              void* d_out, int out_size, void* d_ws, size_t ws_size,
                              hipStream_t stream) {
    const int*   x    = (const int*)d_in[0];
    const int*   ei   = (const int*)d_in[1];
    const int*   home = (const int*)d_in[2];
    const int*   away = (const int*)d_in[3];
    const float* emb  = (const float*)d_in[4];
    const float* W1   = (const float*)d_in[5];
    const float* b1   = (const float*)d_in[6];
    const float* W2   = (const float*)d_in[7];
    const float* b2   = (const float*)d_in[8];
    const float* lw1  = (const float*)d_in[9];
    const float* lb1  = (const float*)d_in[10];
    const float* lw2  = (const float*)d_in[11];
    const float* lb2  = (const float*)d_in[12];
    const float* lw3  = (const float*)d_in[13];
    const float* lb3  = (const float*)d_in[14];
    float* out = (float*)d_out;

    const int nN = in_sizes[0];       // 100000
    const int nE = in_sizes[1] / 2;   // 5M
    const int nM = in_sizes[2];       // 1M
    const int* src = ei;
    const int* dst = ei + nE;
    const int B = 256;

    const int nb1 = (nE + P1_CHUNK - 1) / P1_CHUNK;
    const int ghN = NBK * nb1;
    const int nbs = (ghN + SBLK - 1) / SBLK;
    const size_t paccN = (size_t)NBK * SPLIT * 768;   // floats (>= pcnt ints)

    size_t need = (size_t)3 * nN * 16 + (size_t)nE * 4 + (size_t)(ghN + 1) * 4 +
                  paccN * 4 + (size_t)nN * 4 + (size_t)(nbs + 8) * 4;

    if (nN <= NBK * 256 && ws_size >= need && nbs <= SBLK) {
        char* w = (char*)d_ws;
        float4* hd0 = (float4*)w;                 w += (size_t)nN * 16;
        float4* hd2 = (float4*)w;                 w += (size_t)nN * 16;
        float4* h2  = (float4*)w;                 w += (size_t)nN * 16;
        u32* bkt  = (u32*)w;                      w += (size_t)nE * 4;
        float* pacc = (float*)w;                  w += paccN * 4;
        int* pcnt = (int*)pacc;                   // sequential reuse
        int* gh   = (int*)w;                      w += (size_t)(ghN + 1) * 4;
        float* dinv = (float*)w;                  w += (size_t)nN * 4;
        int* bsum = (int*)w;

        k_p1hist<<<nb1, P1_T, 0, stream>>>(dst, gh, nE, nb1);
        g_scanA<<<nbs, SBLK, 0, stream>>>(gh, gh, bsum, ghN);
        g_scanB<<<1, SBLK, 0, stream>>>(bsum, nbs);
        g_scanC<<<(ghN + B - 1) / B, B, 0, stream>>>(gh, bsum, ghN, nE);
        k_p1scatter<<<nb1, P1_T, 0, stream>>>(src, dst, gh, bkt, nE, nb1);
        k_cnt<<<NBK * SPLIT, P2_T, 0, stream>>>(bkt, gh, pcnt, nE, nb1);
        k_node<<<(nN + B - 1) / B, B, 0, stream>>>(pcnt, x, emb, dinv, hd0, nN);
        k_agg<<<NBK * SPLIT, P2_T, 0, stream>>>(bkt, gh, hd0, pacc, nE, nb1);
        k_fin1<<<(nN + B - 1) / B, B, 0, stream>>>(pacc, dinv, hd0, W1, b1, W2,
                                                   hd2, nN);
        k_agg<<<NBK * SPLIT, P2_T, 0, stream>>>(bkt, gh, hd2, pacc, nE, nb1);
        k_fin2<<<(nN + B - 1) / B, B, 0, stream>>>(pacc, dinv, hd2, b2, h2, nN);
        k_mlp4<<<(nM + B - 1) / B, B, 0, stream>>>(home, away, h2,
                                                   lw1, lb1, lw2, lb2, lw3, lb3, out, nM);
    } else {
        // fallback: atomic CSR build
        char* w = (char*)d_ws;
        float4* hd0 = (float4*)w;                 w += (size_t)nN * 16;
        float4* hd2 = (float4*)w;                 w += (size_t)nN * 16;
        float4* h2  = (float4*)w;                 w += (size_t)nN * 16;
        int* csr  = (int*)w;                      w += (size_t)nE * 4;
        int* cnt  = (int*)w;                      w += (size_t)(nN + 1) * 4;
        int* off  = (int*)w;                      w += (size_t)(nN + 1) * 4;
        int* cur  = (int*)w;                      w += (size_t)nN * 4;
        float* dinv = (float*)w;                  w += (size_t)nN * 4;
        int* bsum = (int*)w;

        const int nTot = nN + 1;
        const int nbScan = (nTot + SBLK - 1) / SBLK;

        hipMemsetAsync(cnt, 0, (size_t)nTot * sizeof(int), stream);
        k_hist<<<(nE + B - 1) / B, B, 0, stream>>>(dst, cnt, nE);
        g_scanA<<<nbScan, SBLK, 0, stream>>>(cnt, off, bsum, nTot);
        g_scanB<<<1, SBLK, 0, stream>>>(bsum, nbScan);
        g_scanC<<<(nTot + B - 1) / B, B, 0, stream>>>(off, bsum, nTot - 1, nE);
        k_prep<<<(nN + B - 1) / B, B, 0, stream>>>(off, cnt, dinv, cur, nN);
        k_hd0<<<(nN + B - 1) / B, B, 0, stream>>>(x, emb, dinv, hd0, nN);
        k_place<<<(nE + B - 1) / B, B, 0, stream>>>(src, dst, cur, csr, nE);
        k_gather1w<<<((size_t)nN * 64 + B - 1) / B, B, 0, stream>>>(off, csr, hd0, dinv,
                                                                    W1, b1, W2, hd2, nN);
        k_gather2<<<((size_t)nN * 16 + B - 1) / B, B, 0, stream>>>(off, csr, hd2,
                                                                   dinv, b2, h2, nN);
        k_mlp4<<<(nM + B - 1) / B, B, 0, stream>>>(home, away, h2,
                                                   lw1, lb1, lw2, lb2, lw3, lb3, out, nM);
    }
}

// Round 6
// 145.421 us; speedup vs baseline: 1.8192x; 1.8192x over previous
//
#include <hip/hip_runtime.h>

typedef unsigned int u32;
typedef unsigned short u16;

static __device__ __forceinline__ float leaky(float v) {
    return v >= 0.0f ? v : 0.01f * v;
}

#define P1_CHUNK 4096
#define P1_T 256
#define NBK 512            // buckets = dst>>8  (requires nN <= 131072)
#define P2_T 256
#define ASPLIT 2           // sub-blocks per bucket (agg/cnt)
#define ACAP 8192          // LDS staging cap per sub-block (mean ~6400, +30 sigma)
#define SBLK 1024

// ================= pass 1: bucket histogram (bin-major gh) =================
__global__ void k_p1hist(const int* __restrict__ dst, int* __restrict__ gh,
                         int nE, int nb) {
    __shared__ int hist[NBK];
    int t = threadIdx.x;
    hist[t] = 0; hist[t + 256] = 0;
    __syncthreads();
    int base = blockIdx.x * P1_CHUNK;
    int lim = min(P1_CHUNK, nE - base);
    if (lim == P1_CHUNK) {
        const int4* p = (const int4*)(dst + base);
        for (int i = t; i < P1_CHUNK / 4; i += P1_T) {
            int4 v = p[i];
            atomicAdd(&hist[v.x >> 8], 1);
            atomicAdd(&hist[v.y >> 8], 1);
            atomicAdd(&hist[v.z >> 8], 1);
            atomicAdd(&hist[v.w >> 8], 1);
        }
    } else {
        for (int i = t; i < lim; i += P1_T)
            atomicAdd(&hist[dst[base + i] >> 8], 1);
    }
    __syncthreads();
    gh[t * nb + blockIdx.x] = hist[t];
    gh[(t + 256) * nb + blockIdx.x] = hist[t + 256];
}

// ================= generic scan (exclusive), in-place safe =================
__global__ void g_scanA(const int* __restrict__ in, int* __restrict__ out,
                        int* __restrict__ bsum, int n) {
    __shared__ int s[SBLK];
    int t = threadIdx.x, i = blockIdx.x * SBLK + t;
    int v = (i < n) ? in[i] : 0;
    s[t] = v;
    for (int o = 1; o < SBLK; o <<= 1) {
        __syncthreads();
        int x = (t >= o) ? s[t - o] : 0;
        __syncthreads();
        s[t] += x;
    }
    __syncthreads();
    if (i < n) out[i] = s[t] - v;
    if (t == SBLK - 1) bsum[blockIdx.x] = s[t];
}
__global__ void g_scanB(int* __restrict__ bsum, int nb) {
    __shared__ int s[SBLK];
    int t = threadIdx.x;
    int v = (t < nb) ? bsum[t] : 0;
    s[t] = v;
    for (int o = 1; o < SBLK; o <<= 1) {
        __syncthreads();
        int x = (t >= o) ? s[t - o] : 0;
        __syncthreads();
        s[t] += x;
    }
    __syncthreads();
    if (t < nb) bsum[t] = s[t] - v;
}
__global__ void g_scanC(int* __restrict__ out, const int* __restrict__ bsum,
                        int n, int total) {
    int i = blockIdx.x * blockDim.x + threadIdx.x;
    if (i < n) out[i] += bsum[i / SBLK];
    if (i == 0) out[n] = total;           // sentinel gh[ghN] = nE
}

// ====== pass 1 scatter: single edge pass, counts from scanned gh diffs =====
__global__ void k_p1scatter(const int* __restrict__ src, const int* __restrict__ dst,
                            const int* __restrict__ gh, u32* __restrict__ bkt,
                            int nE, int nb) {
    __shared__ int cur[NBK];
    __shared__ int loff[NBK];
    __shared__ int gb[NBK];
    __shared__ int sc[NBK];
    __shared__ u32 pay[P1_CHUNK];
    __shared__ u16 bb[P1_CHUNK];
    int t = threadIdx.x;
    int blk = blockIdx.x;
    int idx0 = t * nb + blk;
    int idx1 = (t + 256) * nb + blk;
    int g0 = gh[idx0], c0 = gh[idx0 + 1] - g0;
    int g1 = gh[idx1], c1 = gh[idx1 + 1] - g1;
    gb[t] = g0; gb[t + 256] = g1;
    sc[t] = c0; sc[t + 256] = c1;
    for (int o = 1; o < NBK; o <<= 1) {
        __syncthreads();
        int a0 = (t >= o) ? sc[t - o] : 0;
        int a1 = (t + 256 >= o) ? sc[t + 256 - o] : 0;
        __syncthreads();
        sc[t] += a0; sc[t + 256] += a1;
    }
    __syncthreads();
    loff[t] = sc[t] - c0;           loff[t + 256] = sc[t + 256] - c1;
    cur[t] = loff[t];               cur[t + 256] = loff[t + 256];
    __syncthreads();
    int base = blk * P1_CHUNK;
    int lim = min(P1_CHUNK, nE - base);
    int n4 = lim >> 2;
    const int4* d4p = (const int4*)(dst + base);
    const int4* s4p = (const int4*)(src + base);
    for (int i = t; i < n4; i += P1_T) {
        int4 d4 = d4p[i];
        int4 s4 = s4p[i];
        int b, r;
        b = d4.x >> 8; r = atomicAdd(&cur[b], 1);
        pay[r] = (u32)(((d4.x & 255) << 17) | s4.x); bb[r] = (u16)b;
        b = d4.y >> 8; r = atomicAdd(&cur[b], 1);
        pay[r] = (u32)(((d4.y & 255) << 17) | s4.y); bb[r] = (u16)b;
        b = d4.z >> 8; r = atomicAdd(&cur[b], 1);
        pay[r] = (u32)(((d4.z & 255) << 17) | s4.z); bb[r] = (u16)b;
        b = d4.w >> 8; r = atomicAdd(&cur[b], 1);
        pay[r] = (u32)(((d4.w & 255) << 17) | s4.w); bb[r] = (u16)b;
    }
    for (int i = (n4 << 2) + t; i < lim; i += P1_T) {
        int d = dst[base + i], s = src[base + i];
        int b = d >> 8;
        int r = atomicAdd(&cur[b], 1);
        pay[r] = (u32)(((d & 255) << 17) | s);
        bb[r] = (u16)b;
    }
    __syncthreads();
    for (int i = t; i < lim; i += P1_T) {
        int b = bb[i];
        bkt[gb[b] + (i - loff[b])] = pay[i];
    }
}

// ====== per-(bucket,split) bin histogram -> partial counts (int atomics) ===
__global__ void k_cnt(const u32* __restrict__ bkt, const int* __restrict__ gh,
                      int* __restrict__ pcnt, int nE, int nb) {
    __shared__ int h[256];
    int t = threadIdx.x;
    int blk = blockIdx.x, b = blk >> 1, s = blk & 1;
    int base = gh[b * nb];
    int end = (b + 1 < NBK) ? gh[(b + 1) * nb] : nE;
    int sz = end - base;
    int chunk = (sz + ASPLIT - 1) / ASPLIT;
    int st = min(base + s * chunk, end);
    int en = min(st + chunk, end);
    h[t] = 0;
    __syncthreads();
    int a0 = min((st + 3) & ~3, en);
    if (st + t < a0) atomicAdd(&h[bkt[st + t] >> 17], 1);
    int vend = a0 + ((en - a0) & ~3);
    for (int i = a0 + t * 4; i < vend; i += P2_T * 4) {
        uint4 v = *(const uint4*)&bkt[i];
        atomicAdd(&h[v.x >> 17], 1);
        atomicAdd(&h[v.y >> 17], 1);
        atomicAdd(&h[v.z >> 17], 1);
        atomicAdd(&h[v.w >> 17], 1);
    }
    if (vend + t < en) atomicAdd(&h[bkt[vend + t] >> 17], 1);
    __syncthreads();
    pcnt[blk * 256 + t] = h[t];
}

// ====== node tables: deg -> dinv, hd0 = emb[x]*dinv ========================
__global__ void k_node(const int* __restrict__ pcnt, const int* __restrict__ x,
                       const float* __restrict__ emb, float* __restrict__ dinv,
                       float4* __restrict__ hd0, int nN) {
    int d = blockIdx.x * blockDim.x + threadIdx.x;
    if (d >= nN) return;
    int b = d >> 8, bin = d & 255;
    int deg = pcnt[(b * 2) * 256 + bin] + pcnt[(b * 2 + 1) * 256 + bin];
    float di = rsqrtf((float)deg + 1.0f);
    dinv[d] = di;
    int xi = x[d] * 3;
    hd0[d] = make_float4(emb[xi] * di, emb[xi + 1] * di, emb[xi + 2] * di, 0.f);
}

// ====== aggS: LDS counting-sort sub-range (int atomics), per-thread-owns-dst
//        serial gather, write fp32 partials (no float atomics anywhere) =====
__global__ __launch_bounds__(256) void k_aggS(
        const u32* __restrict__ bkt, const int* __restrict__ gh,
        const float4* __restrict__ tab, float* __restrict__ pacc,
        int nE, int nb) {
    __shared__ u32 stg[ACAP];
    __shared__ int hcnt[256];
    __shared__ int lo[256];
    __shared__ int cur[256];
    int t = threadIdx.x;
    int blk = blockIdx.x, b = blk >> 1, s = blk & 1;
    int base = gh[b * nb];
    int end = (b + 1 < NBK) ? gh[(b + 1) * nb] : nE;
    int sz = end - base;
    int chunk = (sz + ASPLIT - 1) / ASPLIT;
    int st = min(base + s * chunk, end);
    int en = min(st + chunk, end);
    int n = en - st;
    hcnt[t] = 0;
    __syncthreads();
    // histogram (vectorized, int LDS atomics)
    int a0 = min((st + 3) & ~3, en);
    if (st + t < a0) atomicAdd(&hcnt[bkt[st + t] >> 17], 1);
    int vend = a0 + ((en - a0) & ~3);
    for (int i = a0 + t * 4; i < vend; i += P2_T * 4) {
        uint4 v = *(const uint4*)&bkt[i];
        atomicAdd(&hcnt[v.x >> 17], 1);
        atomicAdd(&hcnt[v.y >> 17], 1);
        atomicAdd(&hcnt[v.z >> 17], 1);
        atomicAdd(&hcnt[v.w >> 17], 1);
    }
    if (vend + t < en) atomicAdd(&hcnt[bkt[vend + t] >> 17], 1);
    __syncthreads();
    int c = hcnt[t];
    lo[t] = c;
    for (int o = 1; o < 256; o <<= 1) {
        __syncthreads();
        int a = (t >= o) ? lo[t - o] : 0;
        __syncthreads();
        lo[t] += a;
    }
    __syncthreads();
    int mylo = lo[t] - c;            // exclusive offset of my bin
    cur[t] = mylo;
    __syncthreads();

    float s0 = 0.f, s1 = 0.f, s2 = 0.f;
    if (n <= ACAP) {
        // rank & stage (int LDS atomics)
        if (st + t < a0) {
            u32 v = bkt[st + t];
            stg[atomicAdd(&cur[v >> 17], 1)] = v & 0x1FFFFu;
        }
        for (int i = a0 + t * 4; i < vend; i += P2_T * 4) {
            uint4 v = *(const uint4*)&bkt[i];
            stg[atomicAdd(&cur[v.x >> 17], 1)] = v.x & 0x1FFFFu;
            stg[atomicAdd(&cur[v.y >> 17], 1)] = v.y & 0x1FFFFu;
            stg[atomicAdd(&cur[v.z >> 17], 1)] = v.z & 0x1FFFFu;
            stg[atomicAdd(&cur[v.w >> 17], 1)] = v.w & 0x1FFFFu;
        }
        if (vend + t < en) {
            u32 v = bkt[vend + t];
            stg[atomicAdd(&cur[v >> 17], 1)] = v & 0x1FFFFu;
        }
        __syncthreads();
        // per-thread serial gather over contiguous LDS list
        float q0 = 0.f, q1 = 0.f, q2 = 0.f;
        float r0 = 0.f, r1 = 0.f, r2 = 0.f;
        float w0 = 0.f, w1 = 0.f, w2 = 0.f;
        int j = mylo, e = mylo + c;
        for (; j + 4 <= e; j += 4) {
            float4 v0 = tab[stg[j]];
            float4 v1 = tab[stg[j + 1]];
            float4 v2 = tab[stg[j + 2]];
            float4 v3 = tab[stg[j + 3]];
            s0 += v0.x; s1 += v0.y; s2 += v0.z;
            q0 += v1.x; q1 += v1.y; q2 += v1.z;
            r0 += v2.x; r1 += v2.y; r2 += v2.z;
            w0 += v3.x; w1 += v3.y; w2 += v3.z;
        }
        for (; j < e; ++j) {
            float4 v = tab[stg[j]];
            s0 += v.x; s1 += v.y; s2 += v.z;
        }
        s0 += q0 + r0 + w0; s1 += q1 + r1 + w1; s2 += q2 + r2 + w2;
    } else {
        // statistically unreachable fallback: all threads scan sub-range
        for (int i = st; i < en; ++i) {
            u32 v = bkt[i];
            if ((int)(v >> 17) == t) {
                float4 h = tab[v & 0x1FFFFu];
                s0 += h.x; s1 += h.y; s2 += h.z;
            }
        }
    }
    float* p = pacc + (size_t)blk * 768;
    p[t] = s0; p[256 + t] = s1; p[512 + t] = s2;
}

// ====== fin1: combine partials + self, chain @W1->leaky->@W2, *dinv ========
__global__ void k_fin1(const float* __restrict__ pacc, const float* __restrict__ dinv,
                       const float4* __restrict__ hd0,
                       const float* __restrict__ W1, const float* __restrict__ b1,
                       const float* __restrict__ W2,
                       float4* __restrict__ hd2, int nN) {
    int d = blockIdx.x * blockDim.x + threadIdx.x;
    if (d >= nN) return;
    int b = d >> 8, bin = d & 255;
    const float* p0 = pacc + (size_t)(b * 2) * 768 + bin;
    const float* p1 = pacc + (size_t)(b * 2 + 1) * 768 + bin;
    float s0 = p0[0] + p1[0];
    float s1 = p0[256] + p1[256];
    float s2 = p0[512] + p1[512];
    float di = dinv[d];
    float4 self = hd0[d];
    float a0 = di * (s0 + self.x);
    float a1 = di * (s1 + self.y);
    float a2 = di * (s2 + self.z);
    float o0 = 0.f, o1 = 0.f, o2 = 0.f;
#pragma unroll
    for (int k = 0; k < 16; ++k) {
        float p = leaky(a0 * W1[k] + a1 * W1[16 + k] + a2 * W1[32 + k] + b1[k]);
        o0 += p * W2[k * 3 + 0];
        o1 += p * W2[k * 3 + 1];
        o2 += p * W2[k * 3 + 2];
    }
    hd2[d] = make_float4(o0 * di, o1 * di, o2 * di, 0.f);
}

// ====== fin2: combine partials + self, h2 = leaky(di*sum + b2) =============
__global__ void k_fin2(const float* __restrict__ pacc, const float* __restrict__ dinv,
                       const float4* __restrict__ hd2, const float* __restrict__ b2,
                       float4* __restrict__ h2, int nN) {
    int d = blockIdx.x * blockDim.x + threadIdx.x;
    if (d >= nN) return;
    int b = d >> 8, bin = d & 255;
    const float* p0 = pacc + (size_t)(b * 2) * 768 + bin;
    const float* p1 = pacc + (size_t)(b * 2 + 1) * 768 + bin;
    float s0 = p0[0] + p1[0];
    float s1 = p0[256] + p1[256];
    float s2 = p0[512] + p1[512];
    float di = dinv[d];
    float4 self = hd2[d];
    h2[d] = make_float4(leaky(di * (s0 + self.x) + b2[0]),
                        leaky(di * (s1 + self.y) + b2[1]),
                        leaky(di * (s2 + self.z) + b2[2]), 0.f);
}

// ================= per-match MLP =================
__global__ void k_mlp4(const int* __restrict__ home, const int* __restrict__ away,
                       const float4* __restrict__ h2,
                       const float* __restrict__ lw1, const float* __restrict__ lb1,
                       const float* __restrict__ lw2, const float* __restrict__ lb2,
                       const float* __restrict__ lw3, const float* __restrict__ lb3,
                       float* __restrict__ out, int nM) {
    __shared__ float s[235];
    int t = threadIdx.x;
    if (t < 96)       s[t] = lw1[t];
    else if (t < 112) s[t] = lb1[t - 96];
    else if (t < 208) s[t] = lw2[t - 112];
    else if (t < 214) s[t] = lb2[t - 208];
    else if (t < 232) s[t] = lw3[t - 214];
    else if (t < 235) s[t] = lb3[t - 232];
    __syncthreads();
    const float* sw1 = s;        const float* sb1 = s + 96;
    const float* sw2 = s + 112;  const float* sb2 = s + 208;
    const float* sw3 = s + 214;  const float* sb3 = s + 232;

    int m = blockIdx.x * blockDim.x + threadIdx.x;
    if (m >= nM) return;
    float4 zh = h2[home[m]];
    float4 za = h2[away[m]];
    float z[6] = {zh.x, zh.y, zh.z, za.x, za.y, za.z};

    float t1[16];
#pragma unroll
    for (int k = 0; k < 16; ++k) {
        float p = sb1[k];
#pragma unroll
        for (int j = 0; j < 6; ++j) p += z[j] * sw1[j * 16 + k];
        t1[k] = leaky(p);
    }
    float t2[6];
#pragma unroll
    for (int k = 0; k < 6; ++k) {
        float p = sb2[k];
#pragma unroll
        for (int j = 0; j < 16; ++j) p += t1[j] * sw2[j * 6 + k];
        t2[k] = leaky(p);
    }
#pragma unroll
    for (int k = 0; k < 3; ++k) {
        float p = sb3[k];
#pragma unroll
        for (int j = 0; j < 6; ++j) p += t2[j] * sw3[j * 3 + k];
        out[m * 3 + k] = leaky(p);
    }
}

// ================= fallback: atomic CSR build ===============
__global__ void k_hist(const int* __restrict__ dst, int* __restrict__ cnt, int nE) {
    int e = blockIdx.x * blockDim.x + threadIdx.x;
    if (e < nE) atomicAdd(&cnt[dst[e]], 1);
}
__global__ void k_prep(const int* __restrict__ off, const int* __restrict__ cnt,
                       float* __restrict__ dinv, int* __restrict__ cur, int nN) {
    int i = blockIdx.x * blockDim.x + threadIdx.x;
    if (i >= nN) return;
    dinv[i] = rsqrtf((float)cnt[i] + 1.0f);
    cur[i] = off[i];
}
__global__ void k_hd0(const int* __restrict__ x, const float* __restrict__ emb,
                      const float* __restrict__ dinv, float4* __restrict__ hd0, int nN) {
    int i = blockIdx.x * blockDim.x + threadIdx.x;
    if (i >= nN) return;
    float di = dinv[i];
    int xi = x[i] * 3;
    hd0[i] = make_float4(emb[xi] * di, emb[xi + 1] * di, emb[xi + 2] * di, 0.0f);
}
__global__ void k_place(const int* __restrict__ src, const int* __restrict__ dst,
                        int* __restrict__ cur, int* __restrict__ csr, int nE) {
    int e = blockIdx.x * blockDim.x + threadIdx.x;
    if (e >= nE) return;
    int p = atomicAdd(&cur[dst[e]], 1);
    csr[p] = src[e];
}
__global__ void k_gather1w(const int* __restrict__ off, const int* __restrict__ csr,
                           const float4* __restrict__ hd0, const float* __restrict__ dinv,
                           const float* __restrict__ W1, const float* __restrict__ b1,
                           const float* __restrict__ W2,
                           float4* __restrict__ hd2, int nN) {
    int g = blockIdx.x * blockDim.x + threadIdx.x;
    int d = g >> 6, lane = threadIdx.x & 63;
    if (d >= nN) return;
    int e0 = off[d], e1 = off[d + 1];
    float sx = 0.f, sy = 0.f, sz = 0.f;
    for (int e = e0 + lane; e < e1; e += 64) {
        float4 v = hd0[csr[e]];
        sx += v.x; sy += v.y; sz += v.z;
    }
    for (int o = 32; o; o >>= 1) {
        sx += __shfl_down(sx, o);
        sy += __shfl_down(sy, o);
        sz += __shfl_down(sz, o);
    }
    if (lane == 0) {
        float di = dinv[d];
        float4 self = hd0[d];
        float a0 = di * (sx + self.x);
        float a1 = di * (sy + self.y);
        float a2 = di * (sz + self.z);
        float o0 = 0.f, o1 = 0.f, o2 = 0.f;
#pragma unroll
        for (int k = 0; k < 16; ++k) {
            float p = leaky(a0 * W1[k] + a1 * W1[16 + k] + a2 * W1[32 + k] + b1[k]);
            o0 += p * W2[k * 3 + 0];
            o1 += p * W2[k * 3 + 1];
            o2 += p * W2[k * 3 + 2];
        }
        hd2[d] = make_float4(o0 * di, o1 * di, o2 * di, 0.0f);
    }
}
__global__ void k_gather2(const int* __restrict__ off, const int* __restrict__ csr,
                          const float4* __restrict__ hd2, const float* __restrict__ dinv,
                          const float* __restrict__ b2,
                          float4* __restrict__ h2, int nN) {
    int g = blockIdx.x * blockDim.x + threadIdx.x;
    int d = g >> 4, lane = threadIdx.x & 15;
    if (d >= nN) return;
    int e0 = off[d], e1 = off[d + 1];
    float s0 = 0.f, s1 = 0.f, s2 = 0.f;
    for (int e = e0 + lane; e < e1; e += 16) {
        float4 v = hd2[csr[e]];
        s0 += v.x; s1 += v.y; s2 += v.z;
    }
    for (int o = 8; o; o >>= 1) {
        s0 += __shfl_down(s0, o, 16);
        s1 += __shfl_down(s1, o, 16);
        s2 += __shfl_down(s2, o, 16);
    }
    if (lane == 0) {
        float di = dinv[d];
        float4 self = hd2[d];
        h2[d] = make_float4(leaky(di * (s0 + self.x) + b2[0]),
                            leaky(di * (s1 + self.y) + b2[1]),
                            leaky(di * (s2 + self.z) + b2[2]), 0.f);
    }
}

// ================= launch =================
extern "C" void kernel_launch(void* const* d_in, const int* in_sizes, int n_in,
                              void* d_out, int out_size, void* d_ws, size_t ws_size,
                              hipStream_t stream) {
    const int*   x    = (const int*)d_in[0];
    const int*   ei   = (const int*)d_in[1];
    const int*   home = (const int*)d_in[2];
    const int*   away = (const int*)d_in[3];
    const float* emb  = (const float*)d_in[4];
    const float* W1   = (const float*)d_in[5];
    const float* b1   = (const float*)d_in[6];
    const float* W2   = (const float*)d_in[7];
    const float* b2   = (const float*)d_in[8];
    const float* lw1  = (const float*)d_in[9];
    const float* lb1  = (const float*)d_in[10];
    const float* lw2  = (const float*)d_in[11];
    const float* lb2  = (const float*)d_in[12];
    const float* lw3  = (const float*)d_in[13];
    const float* lb3  = (const float*)d_in[14];
    float* out = (float*)d_out;

    const int nN = in_sizes[0];       // 100000
    const int nE = in_sizes[1] / 2;   // 5M
    const int nM = in_sizes[2];       // 1M
    const int* src = ei;
    const int* dst = ei + nE;
    const int B = 256;

    const int nb1 = (nE + P1_CHUNK - 1) / P1_CHUNK;
    const int ghN = NBK * nb1;
    const int nbs = (ghN + SBLK - 1) / SBLK;
    const size_t paccN = (size_t)NBK * ASPLIT * 768;   // floats (>= pcnt ints)

    size_t need = (size_t)3 * nN * 16 + (size_t)nE * 4 + (size_t)(ghN + 1) * 4 +
                  paccN * 4 + (size_t)nN * 4 + (size_t)(nbs + 8) * 4;

    if (nN <= NBK * 256 && ws_size >= need && nbs <= SBLK) {
        char* w = (char*)d_ws;
        float4* hd0 = (float4*)w;                 w += (size_t)nN * 16;
        float4* hd2 = (float4*)w;                 w += (size_t)nN * 16;
        float4* h2  = (float4*)w;                 w += (size_t)nN * 16;
        u32* bkt  = (u32*)w;                      w += (size_t)nE * 4;
        float* pacc = (float*)w;                  w += paccN * 4;
        int* pcnt = (int*)pacc;                   // sequential reuse
        int* gh   = (int*)w;                      w += (size_t)(ghN + 1) * 4;
        float* dinv = (float*)w;                  w += (size_t)nN * 4;
        int* bsum = (int*)w;

        k_p1hist<<<nb1, P1_T, 0, stream>>>(dst, gh, nE, nb1);
        g_scanA<<<nbs, SBLK, 0, stream>>>(gh, gh, bsum, ghN);
        g_scanB<<<1, SBLK, 0, stream>>>(bsum, nbs);
        g_scanC<<<(ghN + B - 1) / B, B, 0, stream>>>(gh, bsum, ghN, nE);
        k_p1scatter<<<nb1, P1_T, 0, stream>>>(src, dst, gh, bkt, nE, nb1);
        k_cnt<<<NBK * ASPLIT, P2_T, 0, stream>>>(bkt, gh, pcnt, nE, nb1);
        k_node<<<(nN + B - 1) / B, B, 0, stream>>>(pcnt, x, emb, dinv, hd0, nN);
        k_aggS<<<NBK * ASPLIT, P2_T, 0, stream>>>(bkt, gh, hd0, pacc, nE, nb1);
        k_fin1<<<(nN + B - 1) / B, B, 0, stream>>>(pacc, dinv, hd0, W1, b1, W2,
                                                   hd2, nN);
        k_aggS<<<NBK * ASPLIT, P2_T, 0, stream>>>(bkt, gh, hd2, pacc, nE, nb1);
        k_fin2<<<(nN + B - 1) / B, B, 0, stream>>>(pacc, dinv, hd2, b2, h2, nN);
        k_mlp4<<<(nM + B - 1) / B, B, 0, stream>>>(home, away, h2,
                                                   lw1, lb1, lw2, lb2, lw3, lb3, out, nM);
    } else {
        // fallback: atomic CSR build
        char* w = (char*)d_ws;
        float4* hd0 = (float4*)w;                 w += (size_t)nN * 16;
        float4* hd2 = (float4*)w;                 w += (size_t)nN * 16;
        float4* h2  = (float4*)w;                 w += (size_t)nN * 16;
        int* csr  = (int*)w;                      w += (size_t)nE * 4;
        int* cnt  = (int*)w;                      w += (size_t)(nN + 1) * 4;
        int* off  = (int*)w;                      w += (size_t)(nN + 1) * 4;
        int* cur  = (int*)w;                      w += (size_t)nN * 4;
        float* dinv = (float*)w;                  w += (size_t)nN * 4;
        int* bsum = (int*)w;

        const int nTot = nN + 1;
        const int nbScan = (nTot + SBLK - 1) / SBLK;

        hipMemsetAsync(cnt, 0, (size_t)nTot * sizeof(int), stream);
        k_hist<<<(nE + B - 1) / B, B, 0, stream>>>(dst, cnt, nE);
        g_scanA<<<nbScan, SBLK, 0, stream>>>(cnt, off, bsum, nTot);
        g_scanB<<<1, SBLK, 0, stream>>>(bsum, nbScan);
        g_scanC<<<(nTot + B - 1) / B, B, 0, stream>>>(off, bsum, nTot - 1, nE);
        k_prep<<<(nN + B - 1) / B, B, 0, stream>>>(off, cnt, dinv, cur, nN);
        k_hd0<<<(nN + B - 1) / B, B, 0, stream>>>(x, emb, dinv, hd0, nN);
        k_place<<<(nE + B - 1) / B, B, 0, stream>>>(src, dst, cur, csr, nE);
        k_gather1w<<<((size_t)nN * 64 + B - 1) / B, B, 0, stream>>>(off, csr, hd0, dinv,
                                                                    W1, b1, W2, hd2, nN);
        k_gather2<<<((size_t)nN * 16 + B - 1) / B, B, 0, stream>>>(off, csr, hd2,
                                                                   dinv, b2, h2, nN);
        k_mlp4<<<(nM + B - 1) / B, B, 0, stream>>>(home, away, h2,
                                                   lw1, lb1, lw2, lb2, lw3, lb3, out, nM);
    }
}

// Round 8
// 138.145 us; speedup vs baseline: 1.9150x; 1.0527x over previous
//
#include <hip/hip_runtime.h>

typedef unsigned int u32;
typedef unsigned short u16;

static __device__ __forceinline__ float leaky(float v) {
    return v >= 0.0f ? v : 0.01f * v;
}

#define P1_CHUNK 4096
#define P1_T 256
#define NBK 512            // buckets = dst>>8  (requires nN <= 131072)
#define P2_T 256
#define ASPLIT 4           // sub-blocks per bucket for agg kernels
#define SBLK 1024
#define S1F 8388608.0f     // 2^23 fixed-point scale, layer 1
#define S2F 2097152.0f     // 2^21 fixed-point scale, layer 2

// GH(i): global exclusive-scan value without the scanC pass
static __device__ __forceinline__ int ghat(const int* __restrict__ gh,
                                           const int* __restrict__ bsum,
                                           int i, int ghN, int nE) {
    return (i == ghN) ? nE : gh[i] + bsum[i >> 10];
}

// ================= pass 1: bucket histogram (bin-major gh) =================
__global__ void k_p1hist(const int* __restrict__ dst, int* __restrict__ gh,
                         int nE, int nb) {
    __shared__ int hist[NBK];
    int t = threadIdx.x;
    hist[t] = 0; hist[t + 256] = 0;
    __syncthreads();
    int base = blockIdx.x * P1_CHUNK;
    int lim = min(P1_CHUNK, nE - base);
    if (lim == P1_CHUNK) {
        const int4* p = (const int4*)(dst + base);
        for (int i = t; i < P1_CHUNK / 4; i += P1_T) {
            int4 v = p[i];
            atomicAdd(&hist[v.x >> 8], 1);
            atomicAdd(&hist[v.y >> 8], 1);
            atomicAdd(&hist[v.z >> 8], 1);
            atomicAdd(&hist[v.w >> 8], 1);
        }
    } else {
        for (int i = t; i < lim; i += P1_T)
            atomicAdd(&hist[dst[base + i] >> 8], 1);
    }
    __syncthreads();
    gh[t * nb + blockIdx.x] = hist[t];
    gh[(t + 256) * nb + blockIdx.x] = hist[t + 256];
}

// ================= scan: per-1024-chunk exclusive + block sums =============
__global__ void g_scanA(const int* __restrict__ in, int* __restrict__ out,
                        int* __restrict__ bsum, int n) {
    __shared__ int s[SBLK];
    int t = threadIdx.x, i = blockIdx.x * SBLK + t;
    int v = (i < n) ? in[i] : 0;
    s[t] = v;
    for (int o = 1; o < SBLK; o <<= 1) {
        __syncthreads();
        int x = (t >= o) ? s[t - o] : 0;
        __syncthreads();
        s[t] += x;
    }
    __syncthreads();
    if (i < n) out[i] = s[t] - v;
    if (t == SBLK - 1) bsum[blockIdx.x] = s[t];
}
__global__ void g_scanB(int* __restrict__ bsum, int nb) {
    __shared__ int s[SBLK];
    int t = threadIdx.x;
    int v = (t < nb) ? bsum[t] : 0;
    s[t] = v;
    for (int o = 1; o < SBLK; o <<= 1) {
        __syncthreads();
        int x = (t >= o) ? s[t - o] : 0;
        __syncthreads();
        s[t] += x;
    }
    __syncthreads();
    if (t < nb) bsum[t] = s[t] - v;
}
__global__ void g_scanC(int* __restrict__ out, const int* __restrict__ bsum,
                        int n, int total) {
    int i = blockIdx.x * blockDim.x + threadIdx.x;
    if (i < n) out[i] += bsum[i / SBLK];
    if (i == 0) out[n] = total;
}

// ====== pass 1 scatter: single edge pass, counts from GH diffs =============
__global__ void k_p1scatter(const int* __restrict__ src, const int* __restrict__ dst,
                            const int* __restrict__ gh, const int* __restrict__ bsum,
                            u32* __restrict__ bkt, int nE, int nb, int ghN) {
    __shared__ int cur[NBK];
    __shared__ int loff[NBK];
    __shared__ int gb[NBK];
    __shared__ int sc[NBK];
    __shared__ u32 pay[P1_CHUNK];
    __shared__ u16 bb[P1_CHUNK];
    int t = threadIdx.x;
    int blk = blockIdx.x;
    int idx0 = t * nb + blk;
    int idx1 = (t + 256) * nb + blk;
    int g0 = ghat(gh, bsum, idx0, ghN, nE);
    int c0 = ghat(gh, bsum, idx0 + 1, ghN, nE) - g0;
    int g1 = ghat(gh, bsum, idx1, ghN, nE);
    int c1 = ghat(gh, bsum, idx1 + 1, ghN, nE) - g1;
    gb[t] = g0; gb[t + 256] = g1;
    sc[t] = c0; sc[t + 256] = c1;
    for (int o = 1; o < NBK; o <<= 1) {
        __syncthreads();
        int a0 = (t >= o) ? sc[t - o] : 0;
        int a1 = (t + 256 >= o) ? sc[t + 256 - o] : 0;
        __syncthreads();
        sc[t] += a0; sc[t + 256] += a1;
    }
    __syncthreads();
    loff[t] = sc[t] - c0;           loff[t + 256] = sc[t + 256] - c1;
    cur[t] = loff[t];               cur[t + 256] = loff[t + 256];
    __syncthreads();
    int base = blk * P1_CHUNK;
    int lim = min(P1_CHUNK, nE - base);
    int n4 = lim >> 2;
    const int4* d4p = (const int4*)(dst + base);
    const int4* s4p = (const int4*)(src + base);
    for (int i = t; i < n4; i += P1_T) {
        int4 d4 = d4p[i];
        int4 s4 = s4p[i];
        int b, r;
        b = d4.x >> 8; r = atomicAdd(&cur[b], 1);
        pay[r] = (u32)(((d4.x & 255) << 17) | s4.x); bb[r] = (u16)b;
        b = d4.y >> 8; r = atomicAdd(&cur[b], 1);
        pay[r] = (u32)(((d4.y & 255) << 17) | s4.y); bb[r] = (u16)b;
        b = d4.z >> 8; r = atomicAdd(&cur[b], 1);
        pay[r] = (u32)(((d4.z & 255) << 17) | s4.z); bb[r] = (u16)b;
        b = d4.w >> 8; r = atomicAdd(&cur[b], 1);
        pay[r] = (u32)(((d4.w & 255) << 17) | s4.w); bb[r] = (u16)b;
    }
    for (int i = (n4 << 2) + t; i < lim; i += P1_T) {
        int d = dst[base + i], s = src[base + i];
        int b = d >> 8;
        int r = atomicAdd(&cur[b], 1);
        pay[r] = (u32)(((d & 255) << 17) | s);
        bb[r] = (u16)b;
    }
    __syncthreads();
    for (int i = t; i < lim; i += P1_T) {
        int b = bb[i];
        bkt[gb[b] + (i - loff[b])] = pay[i];
    }
}

// ====== cnt1: whole-bucket histogram -> dinv + hd0 directly ================
__global__ void k_cnt1(const u32* __restrict__ bkt, const int* __restrict__ gh,
                       const int* __restrict__ bsum,
                       const int* __restrict__ x, const float* __restrict__ emb,
                       float* __restrict__ dinv, float4* __restrict__ hd0,
                       int nE, int nb, int ghN, int nN) {
    __shared__ int h[256];
    int t = threadIdx.x, b = blockIdx.x;
    int base = ghat(gh, bsum, b * nb, ghN, nE);
    int end  = (b + 1 < NBK) ? ghat(gh, bsum, (b + 1) * nb, ghN, nE) : nE;
    h[t] = 0;
    __syncthreads();
    int a0 = min((base + 3) & ~3, end);
    if (base + t < a0) atomicAdd(&h[bkt[base + t] >> 17], 1);
    int vend = a0 + ((end - a0) & ~3);
    for (int i = a0 + t * 4; i < vend; i += P2_T * 4) {
        uint4 v = *(const uint4*)&bkt[i];
        atomicAdd(&h[v.x >> 17], 1);
        atomicAdd(&h[v.y >> 17], 1);
        atomicAdd(&h[v.z >> 17], 1);
        atomicAdd(&h[v.w >> 17], 1);
    }
    if (vend + t < end) atomicAdd(&h[bkt[vend + t] >> 17], 1);
    __syncthreads();
    int d = b * 256 + t;
    if (d < nN) {
        float di = rsqrtf((float)h[t] + 1.0f);
        dinv[d] = di;
        int xi = x[d] * 3;
        hd0[d] = make_float4(emb[xi] * di, emb[xi + 1] * di, emb[xi + 2] * di, 0.f);
    }
}

// ====== aggI: fixed-point LDS accumulation (int atomics only) ==============
// acc is interleaved acc[bin*3+c]; write-out DE-INTERLEAVES to planar pacc
// (p[bin], p[bin+256], p[bin+512]) to match k_fin1/k_fin2.  <-- R6 bugfix
__global__ __launch_bounds__(256) void k_aggI(
        const u32* __restrict__ bkt, const int* __restrict__ gh,
        const int* __restrict__ bsum,
        const float4* __restrict__ tab, float* __restrict__ pacc,
        int nE, int nb, int ghN, float scale, float inv_scale) {
    __shared__ int acc[768];
    int t = threadIdx.x;
    int blk = blockIdx.x, b = blk >> 2, s = blk & 3;
    int base = ghat(gh, bsum, b * nb, ghN, nE);
    int end  = (b + 1 < NBK) ? ghat(gh, bsum, (b + 1) * nb, ghN, nE) : nE;
    int sz = end - base;
    int chunk = (sz + ASPLIT - 1) / ASPLIT;
    int st = min(base + s * chunk, end);
    int en = min(st + chunk, end);
    acc[t] = 0; acc[t + 256] = 0; acc[t + 512] = 0;
    __syncthreads();
    int a0 = min((st + 3) & ~3, en);
    if (st + t < a0) {
        u32 v = bkt[st + t];
        float4 h = tab[v & 0x1FFFFu];
        int bin = (int)(v >> 17) * 3;
        atomicAdd(&acc[bin + 0], __float2int_rn(h.x * scale));
        atomicAdd(&acc[bin + 1], __float2int_rn(h.y * scale));
        atomicAdd(&acc[bin + 2], __float2int_rn(h.z * scale));
    }
    int vend = a0 + ((en - a0) & ~3);
    for (int i = a0 + t * 4; i < vend; i += P2_T * 4) {
        uint4 v = *(const uint4*)&bkt[i];
        float4 h0 = tab[v.x & 0x1FFFFu];
        float4 h1 = tab[v.y & 0x1FFFFu];
        float4 h2 = tab[v.z & 0x1FFFFu];
        float4 h3 = tab[v.w & 0x1FFFFu];
        int b0 = (int)(v.x >> 17) * 3, b1 = (int)(v.y >> 17) * 3;
        int b2 = (int)(v.z >> 17) * 3, b3 = (int)(v.w >> 17) * 3;
        atomicAdd(&acc[b0 + 0], __float2int_rn(h0.x * scale));
        atomicAdd(&acc[b0 + 1], __float2int_rn(h0.y * scale));
        atomicAdd(&acc[b0 + 2], __float2int_rn(h0.z * scale));
        atomicAdd(&acc[b1 + 0], __float2int_rn(h1.x * scale));
        atomicAdd(&acc[b1 + 1], __float2int_rn(h1.y * scale));
        atomicAdd(&acc[b1 + 2], __float2int_rn(h1.z * scale));
        atomicAdd(&acc[b2 + 0], __float2int_rn(h2.x * scale));
        atomicAdd(&acc[b2 + 1], __float2int_rn(h2.y * scale));
        atomicAdd(&acc[b2 + 2], __float2int_rn(h2.z * scale));
        atomicAdd(&acc[b3 + 0], __float2int_rn(h3.x * scale));
        atomicAdd(&acc[b3 + 1], __float2int_rn(h3.y * scale));
        atomicAdd(&acc[b3 + 2], __float2int_rn(h3.z * scale));
    }
    if (vend + t < en) {
        u32 v = bkt[vend + t];
        float4 h = tab[v & 0x1FFFFu];
        int bin = (int)(v >> 17) * 3;
        atomicAdd(&acc[bin + 0], __float2int_rn(h.x * scale));
        atomicAdd(&acc[bin + 1], __float2int_rn(h.y * scale));
        atomicAdd(&acc[bin + 2], __float2int_rn(h.z * scale));
    }
    __syncthreads();
    float* p = pacc + (size_t)blk * 768;
    p[t]       = (float)acc[t * 3 + 0] * inv_scale;   // planar component 0
    p[t + 256] = (float)acc[t * 3 + 1] * inv_scale;   // planar component 1
    p[t + 512] = (float)acc[t * 3 + 2] * inv_scale;   // planar component 2
}

// ====== fin1: combine partials + self, chain @W1->leaky->@W2, *dinv ========
__global__ void k_fin1(const float* __restrict__ pacc, const float* __restrict__ dinv,
                       const float4* __restrict__ hd0,
                       const float* __restrict__ W1, const float* __restrict__ b1,
                       const float* __restrict__ W2,
                       float4* __restrict__ hd2, int nN) {
    int d = blockIdx.x * blockDim.x + threadIdx.x;
    if (d >= nN) return;
    int b = d >> 8, q = d & 255;
    float s0 = 0.f, s1 = 0.f, s2 = 0.f;
#pragma unroll
    for (int s = 0; s < ASPLIT; ++s) {
        const float* p = pacc + (size_t)(b * ASPLIT + s) * 768;
        s0 += p[q]; s1 += p[q + 256]; s2 += p[q + 512];
    }
    float di = dinv[d];
    float4 self = hd0[d];
    float a0 = di * (s0 + self.x);
    float a1 = di * (s1 + self.y);
    float a2 = di * (s2 + self.z);
    float o0 = 0.f, o1 = 0.f, o2 = 0.f;
#pragma unroll
    for (int k = 0; k < 16; ++k) {
        float p = leaky(a0 * W1[k] + a1 * W1[16 + k] + a2 * W1[32 + k] + b1[k]);
        o0 += p * W2[k * 3 + 0];
        o1 += p * W2[k * 3 + 1];
        o2 += p * W2[k * 3 + 2];
    }
    hd2[d] = make_float4(o0 * di, o1 * di, o2 * di, 0.f);
}

// ====== fin2 ===============================================================
__global__ void k_fin2(const float* __restrict__ pacc, const float* __restrict__ dinv,
                       const float4* __restrict__ hd2, const float* __restrict__ b2,
                       float4* __restrict__ h2, int nN) {
    int d = blockIdx.x * blockDim.x + threadIdx.x;
    if (d >= nN) return;
    int b = d >> 8, q = d & 255;
    float s0 = 0.f, s1 = 0.f, s2 = 0.f;
#pragma unroll
    for (int s = 0; s < ASPLIT; ++s) {
        const float* p = pacc + (size_t)(b * ASPLIT + s) * 768;
        s0 += p[q]; s1 += p[q + 256]; s2 += p[q + 512];
    }
    float di = dinv[d];
    float4 self = hd2[d];
    h2[d] = make_float4(leaky(di * (s0 + self.x) + b2[0]),
                        leaky(di * (s1 + self.y) + b2[1]),
                        leaky(di * (s2 + self.z) + b2[2]), 0.f);
}

// ================= per-match MLP =================
__global__ void k_mlp4(const int* __restrict__ home, const int* __restrict__ away,
                       const float4* __restrict__ h2,
                       const float* __restrict__ lw1, const float* __restrict__ lb1,
                       const float* __restrict__ lw2, const float* __restrict__ lb2,
                       const float* __restrict__ lw3, const float* __restrict__ lb3,
                       float* __restrict__ out, int nM) {
    __shared__ float s[235];
    int t = threadIdx.x;
    if (t < 96)       s[t] = lw1[t];
    else if (t < 112) s[t] = lb1[t - 96];
    else if (t < 208) s[t] = lw2[t - 112];
    else if (t < 214) s[t] = lb2[t - 208];
    else if (t < 232) s[t] = lw3[t - 214];
    else if (t < 235) s[t] = lb3[t - 232];
    __syncthreads();
    const float* sw1 = s;        const float* sb1 = s + 96;
    const float* sw2 = s + 112;  const float* sb2 = s + 208;
    const float* sw3 = s + 214;  const float* sb3 = s + 232;

    int m = blockIdx.x * blockDim.x + threadIdx.x;
    if (m >= nM) return;
    float4 zh = h2[home[m]];
    float4 za = h2[away[m]];
    float z[6] = {zh.x, zh.y, zh.z, za.x, za.y, za.z};

    float t1[16];
#pragma unroll
    for (int k = 0; k < 16; ++k) {
        float p = sb1[k];
#pragma unroll
        for (int j = 0; j < 6; ++j) p += z[j] * sw1[j * 16 + k];
        t1[k] = leaky(p);
    }
    float t2[6];
#pragma unroll
    for (int k = 0; k < 6; ++k) {
        float p = sb2[k];
#pragma unroll
        for (int j = 0; j < 16; ++j) p += t1[j] * sw2[j * 6 + k];
        t2[k] = leaky(p);
    }
#pragma unroll
    for (int k = 0; k < 3; ++k) {
        float p = sb3[k];
#pragma unroll
        for (int j = 0; j < 6; ++j) p += t2[j] * sw3[j * 3 + k];
        out[m * 3 + k] = leaky(p);
    }
}

// ================= fallback: atomic CSR build ===============
__global__ void k_hist(const int* __restrict__ dst, int* __restrict__ cnt, int nE) {
    int e = blockIdx.x * blockDim.x + threadIdx.x;
    if (e < nE) atomicAdd(&cnt[dst[e]], 1);
}
__global__ void k_prep(const int* __restrict__ off, const int* __restrict__ cnt,
                       float* __restrict__ dinv, int* __restrict__ cur, int nN) {
    int i = blockIdx.x * blockDim.x + threadIdx.x;
    if (i >= nN) return;
    dinv[i] = rsqrtf((float)cnt[i] + 1.0f);
    cur[i] = off[i];
}
__global__ void k_hd0(const int* __restrict__ x, const float* __restrict__ emb,
                      const float* __restrict__ dinv, float4* __restrict__ hd0, int nN) {
    int i = blockIdx.x * blockDim.x + threadIdx.x;
    if (i >= nN) return;
    float di = dinv[i];
    int xi = x[i] * 3;
    hd0[i] = make_float4(emb[xi] * di, emb[xi + 1] * di, emb[xi + 2] * di, 0.0f);
}
__global__ void k_place(const int* __restrict__ src, const int* __restrict__ dst,
                        int* __restrict__ cur, int* __restrict__ csr, int nE) {
    int e = blockIdx.x * blockDim.x + threadIdx.x;
    if (e >= nE) return;
    int p = atomicAdd(&cur[dst[e]], 1);
    csr[p] = src[e];
}
__global__ void k_gather1w(const int* __restrict__ off, const int* __restrict__ csr,
                           const float4* __restrict__ hd0, const float* __restrict__ dinv,
                           const float* __restrict__ W1, const float* __restrict__ b1,
                           const float* __restrict__ W2,
                           float4* __restrict__ hd2, int nN) {
    int g = blockIdx.x * blockDim.x + threadIdx.x;
    int d = g >> 6, lane = threadIdx.x & 63;
    if (d >= nN) return;
    int e0 = off[d], e1 = off[d + 1];
    float sx = 0.f, sy = 0.f, sz = 0.f;
    for (int e = e0 + lane; e < e1; e += 64) {
        float4 v = hd0[csr[e]];
        sx += v.x; sy += v.y; sz += v.z;
    }
    for (int o = 32; o; o >>= 1) {
        sx += __shfl_down(sx, o);
        sy += __shfl_down(sy, o);
        sz += __shfl_down(sz, o);
    }
    if (lane == 0) {
        float di = dinv[d];
        float4 self = hd0[d];
        float a0 = di * (sx + self.x);
        float a1 = di * (sy + self.y);
        float a2 = di * (sz + self.z);
        float o0 = 0.f, o1 = 0.f, o2 = 0.f;
#pragma unroll
        for (int k = 0; k < 16; ++k) {
            float p = leaky(a0 * W1[k] + a1 * W1[16 + k] + a2 * W1[32 + k] + b1[k]);
            o0 += p * W2[k * 3 + 0];
            o1 += p * W2[k * 3 + 1];
            o2 += p * W2[k * 3 + 2];
        }
        hd2[d] = make_float4(o0 * di, o1 * di, o2 * di, 0.0f);
    }
}
__global__ void k_gather2(const int* __restrict__ off, const int* __restrict__ csr,
                          const float4* __restrict__ hd2, const float* __restrict__ dinv,
                          const float* __restrict__ b2,
                          float4* __restrict__ h2, int nN) {
    int g = blockIdx.x * blockDim.x + threadIdx.x;
    int d = g >> 4, lane = threadIdx.x & 15;
    if (d >= nN) return;
    int e0 = off[d], e1 = off[d + 1];
    float s0 = 0.f, s1 = 0.f, s2 = 0.f;
    for (int e = e0 + lane; e < e1; e += 16) {
        float4 v = hd2[csr[e]];
        s0 += v.x; s1 += v.y; s2 += v.z;
    }
    for (int o = 8; o; o >>= 1) {
        s0 += __shfl_down(s0, o, 16);
        s1 += __shfl_down(s1, o, 16);
        s2 += __shfl_down(s2, o, 16);
    }
    if (lane == 0) {
        float di = dinv[d];
        float4 self = hd2[d];
        h2[d] = make_float4(leaky(di * (s0 + self.x) + b2[0]),
                            leaky(di * (s1 + self.y) + b2[1]),
                            leaky(di * (s2 + self.z) + b2[2]), 0.f);
    }
}

// ================= launch =================
extern "C" void kernel_launch(void* const* d_in, const int* in_sizes, int n_in,
                              void* d_out, int out_size, void* d_ws, size_t ws_size,
                              hipStream_t stream) {
    const int*   x    = (const int*)d_in[0];
    const int*   ei   = (const int*)d_in[1];
    const int*   home = (const int*)d_in[2];
    const int*   away = (const int*)d_in[3];
    const float* emb  = (const float*)d_in[4];
    const float* W1   = (const float*)d_in[5];
    const float* b1   = (const float*)d_in[6];
    const float* W2   = (const float*)d_in[7];
    const float* b2   = (const float*)d_in[8];
    const float* lw1  = (const float*)d_in[9];
    const float* lb1  = (const float*)d_in[10];
    const float* lw2  = (const float*)d_in[11];
    const float* lb2  = (const float*)d_in[12];
    const float* lw3  = (const float*)d_in[13];
    const float* lb3  = (const float*)d_in[14];
    float* out = (float*)d_out;

    const int nN = in_sizes[0];       // 100000
    const int nE = in_sizes[1] / 2;   // 5M
    const int nM = in_sizes[2];       // 1M
    const int* src = ei;
    const int* dst = ei + nE;
    const int B = 256;

    const int nb1 = (nE + P1_CHUNK - 1) / P1_CHUNK;
    const int ghN = NBK * nb1;
    const int nbs = (ghN + SBLK - 1) / SBLK;
    const size_t paccN = (size_t)NBK * ASPLIT * 768;   // floats

    size_t need = (size_t)3 * nN * 16 + (size_t)nE * 4 + (size_t)(ghN + 1) * 4 +
                  paccN * 4 + (size_t)nN * 4 + (size_t)(nbs + 8) * 4;

    if (nN <= NBK * 256 && ws_size >= need && nbs <= SBLK) {
        char* w = (char*)d_ws;
        float4* hd0 = (float4*)w;                 w += (size_t)nN * 16;
        float4* hd2 = (float4*)w;                 w += (size_t)nN * 16;
        float4* h2  = (float4*)w;                 w += (size_t)nN * 16;
        u32* bkt  = (u32*)w;                      w += (size_t)nE * 4;
        float* pacc = (float*)w;                  w += paccN * 4;
        int* gh   = (int*)w;                      w += (size_t)(ghN + 1) * 4;
        float* dinv = (float*)w;                  w += (size_t)nN * 4;
        int* bsum = (int*)w;

        k_p1hist<<<nb1, P1_T, 0, stream>>>(dst, gh, nE, nb1);
        g_scanA<<<nbs, SBLK, 0, stream>>>(gh, gh, bsum, ghN);
        g_scanB<<<1, SBLK, 0, stream>>>(bsum, nbs);
        k_p1scatter<<<nb1, P1_T, 0, stream>>>(src, dst, gh, bsum, bkt, nE, nb1, ghN);
        k_cnt1<<<NBK, P2_T, 0, stream>>>(bkt, gh, bsum, x, emb, dinv, hd0,
                                         nE, nb1, ghN, nN);
        k_aggI<<<NBK * ASPLIT, P2_T, 0, stream>>>(bkt, gh, bsum, hd0, pacc,
                                                  nE, nb1, ghN, S1F, 1.0f / S1F);
        k_fin1<<<(nN + B - 1) / B, B, 0, stream>>>(pacc, dinv, hd0, W1, b1, W2,
                                                   hd2, nN);
        k_aggI<<<NBK * ASPLIT, P2_T, 0, stream>>>(bkt, gh, bsum, hd2, pacc,
                                                  nE, nb1, ghN, S2F, 1.0f / S2F);
        k_fin2<<<(nN + B - 1) / B, B, 0, stream>>>(pacc, dinv, hd2, b2, h2, nN);
        k_mlp4<<<(nM + B - 1) / B, B, 0, stream>>>(home, away, h2,
                                                   lw1, lb1, lw2, lb2, lw3, lb3, out, nM);
    } else {
        // fallback: atomic CSR build
        char* w = (char*)d_ws;
        float4* hd0 = (float4*)w;                 w += (size_t)nN * 16;
        float4* hd2 = (float4*)w;                 w += (size_t)nN * 16;
        float4* h2  = (float4*)w;                 w += (size_t)nN * 16;
        int* csr  = (int*)w;                      w += (size_t)nE * 4;
        int* cnt  = (int*)w;                      w += (size_t)(nN + 1) * 4;
        int* off  = (int*)w;                      w += (size_t)(nN + 1) * 4;
        int* cur  = (int*)w;                      w += (size_t)nN * 4;
        float* dinv = (float*)w;                  w += (size_t)nN * 4;
        int* bsum = (int*)w;

        const int nTot = nN + 1;
        const int nbScan = (nTot + SBLK - 1) / SBLK;

        hipMemsetAsync(cnt, 0, (size_t)nTot * sizeof(int), stream);
        k_hist<<<(nE + B - 1) / B, B, 0, stream>>>(dst, cnt, nE);
        g_scanA<<<nbScan, SBLK, 0, stream>>>(cnt, off, bsum, nTot);
        g_scanB<<<1, SBLK, 0, stream>>>(bsum, nbScan);
        g_scanC<<<(nTot + B - 1) / B, B, 0, stream>>>(off, bsum, nTot - 1, nE);
        k_prep<<<(nN + B - 1) / B, B, 0, stream>>>(off, cnt, dinv, cur, nN);
        k_hd0<<<(nN + B - 1) / B, B, 0, stream>>>(x, emb, dinv, hd0, nN);
        k_place<<<(nE + B - 1) / B, B, 0, stream>>>(src, dst, cur, csr, nE);
        k_gather1w<<<((size_t)nN * 64 + B - 1) / B, B, 0, stream>>>(off, csr, hd0, dinv,
                                                                    W1, b1, W2, hd2, nN);
        k_gather2<<<((size_t)nN * 16 + B - 1) / B, B, 0, stream>>>(off, csr, hd2,
                                                                   dinv, b2, h2, nN);
        k_mlp4<<<(nM + B - 1) / B, B, 0, stream>>>(home, away, h2,
                                                   lw1, lb1, lw2, lb2, lw3, lb3, out, nM);
    }
}

// Round 9
// 136.950 us; speedup vs baseline: 1.9317x; 1.0087x over previous
//
#include <hip/hip_runtime.h>

typedef unsigned int u32;
typedef unsigned short u16;

static __device__ __forceinline__ float leaky(float v) {
    return v >= 0.0f ? v : 0.01f * v;
}

#define P1_CHUNK 8192
#define P1_T 256
#define NBK 512            // buckets = dst>>8  (requires nN <= 131072)
#define P2_T 256
#define ASPLIT 4           // sub-blocks per bucket for agg kernels
#define SBLK 1024
#define S1F 8388608.0f     // 2^23 fixed-point scale, layer 1
#define S2F 2097152.0f     // 2^21 fixed-point scale, layer 2

// GH(i): global exclusive-scan value without a scanC pass
static __device__ __forceinline__ int ghat(const int* __restrict__ gh,
                                           const int* __restrict__ bsum,
                                           int i, int ghN, int nE) {
    return (i == ghN) ? nE : gh[i] + bsum[i >> 10];
}

// ================= pass 1: bucket histogram (bin-major gh) =================
__global__ void k_p1hist(const int* __restrict__ dst, int* __restrict__ gh,
                         int nE, int nb) {
    __shared__ int hist[NBK];
    int t = threadIdx.x;
    hist[t] = 0; hist[t + 256] = 0;
    __syncthreads();
    int base = blockIdx.x * P1_CHUNK;
    int lim = min(P1_CHUNK, nE - base);
    if (lim == P1_CHUNK) {
        const int4* p = (const int4*)(dst + base);
        for (int i = t; i < P1_CHUNK / 4; i += P1_T) {
            int4 v = p[i];
            atomicAdd(&hist[v.x >> 8], 1);
            atomicAdd(&hist[v.y >> 8], 1);
            atomicAdd(&hist[v.z >> 8], 1);
            atomicAdd(&hist[v.w >> 8], 1);
        }
    } else {
        for (int i = t; i < lim; i += P1_T)
            atomicAdd(&hist[dst[base + i] >> 8], 1);
    }
    __syncthreads();
    gh[t * nb + blockIdx.x] = hist[t];
    gh[(t + 256) * nb + blockIdx.x] = hist[t + 256];
}

// ================= scan: per-1024-chunk exclusive + block sums =============
__global__ void g_scanA(const int* __restrict__ in, int* __restrict__ out,
                        int* __restrict__ bsum, int n) {
    __shared__ int s[SBLK];
    int t = threadIdx.x, i = blockIdx.x * SBLK + t;
    int v = (i < n) ? in[i] : 0;
    s[t] = v;
    for (int o = 1; o < SBLK; o <<= 1) {
        __syncthreads();
        int x = (t >= o) ? s[t - o] : 0;
        __syncthreads();
        s[t] += x;
    }
    __syncthreads();
    if (i < n) out[i] = s[t] - v;
    if (t == SBLK - 1) bsum[blockIdx.x] = s[t];
}
__global__ void g_scanB(int* __restrict__ bsum, int nb) {
    __shared__ int s[SBLK];
    int t = threadIdx.x;
    int v = (t < nb) ? bsum[t] : 0;
    s[t] = v;
    for (int o = 1; o < SBLK; o <<= 1) {
        __syncthreads();
        int x = (t >= o) ? s[t - o] : 0;
        __syncthreads();
        s[t] += x;
    }
    __syncthreads();
    if (t < nb) bsum[t] = s[t] - v;
}
__global__ void g_scanC(int* __restrict__ out, const int* __restrict__ bsum,
                        int n, int total) {
    int i = blockIdx.x * blockDim.x + threadIdx.x;
    if (i < n) out[i] += bsum[i / SBLK];
    if (i == 0) out[n] = total;
}

// ====== pass 1 scatter: single edge pass, counts from GH diffs =============
__global__ __launch_bounds__(256) void k_p1scatter(
        const int* __restrict__ src, const int* __restrict__ dst,
        const int* __restrict__ gh, const int* __restrict__ bsum,
        u32* __restrict__ bkt, int nE, int nb, int ghN) {
    __shared__ int cur[NBK];
    __shared__ int loff[NBK];
    __shared__ int gb[NBK];
    __shared__ int sc[NBK];
    __shared__ u32 pay[P1_CHUNK];
    __shared__ u16 bb[P1_CHUNK];
    int t = threadIdx.x;
    int blk = blockIdx.x;
    int idx0 = t * nb + blk;
    int idx1 = (t + 256) * nb + blk;
    int g0 = ghat(gh, bsum, idx0, ghN, nE);
    int c0 = ghat(gh, bsum, idx0 + 1, ghN, nE) - g0;
    int g1 = ghat(gh, bsum, idx1, ghN, nE);
    int c1 = ghat(gh, bsum, idx1 + 1, ghN, nE) - g1;
    gb[t] = g0; gb[t + 256] = g1;
    sc[t] = c0; sc[t + 256] = c1;
    for (int o = 1; o < NBK; o <<= 1) {
        __syncthreads();
        int a0 = (t >= o) ? sc[t - o] : 0;
        int a1 = (t + 256 >= o) ? sc[t + 256 - o] : 0;
        __syncthreads();
        sc[t] += a0; sc[t + 256] += a1;
    }
    __syncthreads();
    loff[t] = sc[t] - c0;           loff[t + 256] = sc[t + 256] - c1;
    cur[t] = loff[t];               cur[t + 256] = loff[t + 256];
    __syncthreads();
    int base = blk * P1_CHUNK;
    int lim = min(P1_CHUNK, nE - base);
    int n4 = lim >> 2;
    const int4* d4p = (const int4*)(dst + base);
    const int4* s4p = (const int4*)(src + base);
    for (int i = t; i < n4; i += P1_T) {
        int4 d4 = d4p[i];
        int4 s4 = s4p[i];
        int b, r;
        b = d4.x >> 8; r = atomicAdd(&cur[b], 1);
        pay[r] = (u32)(((d4.x & 255) << 17) | s4.x); bb[r] = (u16)b;
        b = d4.y >> 8; r = atomicAdd(&cur[b], 1);
        pay[r] = (u32)(((d4.y & 255) << 17) | s4.y); bb[r] = (u16)b;
        b = d4.z >> 8; r = atomicAdd(&cur[b], 1);
        pay[r] = (u32)(((d4.z & 255) << 17) | s4.z); bb[r] = (u16)b;
        b = d4.w >> 8; r = atomicAdd(&cur[b], 1);
        pay[r] = (u32)(((d4.w & 255) << 17) | s4.w); bb[r] = (u16)b;
    }
    for (int i = (n4 << 2) + t; i < lim; i += P1_T) {
        int d = dst[base + i], s = src[base + i];
        int b = d >> 8;
        int r = atomicAdd(&cur[b], 1);
        pay[r] = (u32)(((d & 255) << 17) | s);
        bb[r] = (u16)b;
    }
    __syncthreads();
    for (int i = t; i < lim; i += P1_T) {
        int b = bb[i];
        bkt[gb[b] + (i - loff[b])] = pay[i];
    }
}

// ====== cnt1: whole-bucket histogram -> dinv + hd0 directly ================
__global__ void k_cnt1(const u32* __restrict__ bkt, const int* __restrict__ gh,
                       const int* __restrict__ bsum,
                       const int* __restrict__ x, const float* __restrict__ emb,
                       float* __restrict__ dinv, float4* __restrict__ hd0,
                       int nE, int nb, int ghN, int nN) {
    __shared__ int h[256];
    int t = threadIdx.x, b = blockIdx.x;
    int base = ghat(gh, bsum, b * nb, ghN, nE);
    int end  = (b + 1 < NBK) ? ghat(gh, bsum, (b + 1) * nb, ghN, nE) : nE;
    h[t] = 0;
    __syncthreads();
    int a0 = min((base + 3) & ~3, end);
    if (base + t < a0) atomicAdd(&h[bkt[base + t] >> 17], 1);
    int vend = a0 + ((end - a0) & ~3);
    for (int i = a0 + t * 4; i < vend; i += P2_T * 4) {
        uint4 v = *(const uint4*)&bkt[i];
        atomicAdd(&h[v.x >> 17], 1);
        atomicAdd(&h[v.y >> 17], 1);
        atomicAdd(&h[v.z >> 17], 1);
        atomicAdd(&h[v.w >> 17], 1);
    }
    if (vend + t < end) atomicAdd(&h[bkt[vend + t] >> 17], 1);
    __syncthreads();
    int d = b * 256 + t;
    if (d < nN) {
        float di = rsqrtf((float)h[t] + 1.0f);
        dinv[d] = di;
        int xi = x[d] * 3;
        hd0[d] = make_float4(emb[xi] * di, emb[xi + 1] * di, emb[xi + 2] * di, 0.f);
    }
}

// ====== aggI: fixed-point LDS accumulation (int atomics only) ==============
// interleaved acc[bin*3+c]; write-out de-interleaves to planar pacc
__global__ __launch_bounds__(256) void k_aggI(
        const u32* __restrict__ bkt, const int* __restrict__ gh,
        const int* __restrict__ bsum,
        const float4* __restrict__ tab, float* __restrict__ pacc,
        int nE, int nb, int ghN, float scale, float inv_scale) {
    __shared__ int acc[768];
    int t = threadIdx.x;
    int blk = blockIdx.x, b = blk >> 2, s = blk & 3;
    int base = ghat(gh, bsum, b * nb, ghN, nE);
    int end  = (b + 1 < NBK) ? ghat(gh, bsum, (b + 1) * nb, ghN, nE) : nE;
    int sz = end - base;
    int chunk = (sz + ASPLIT - 1) / ASPLIT;
    int st = min(base + s * chunk, end);
    int en = min(st + chunk, end);
    acc[t] = 0; acc[t + 256] = 0; acc[t + 512] = 0;
    __syncthreads();
    int a0 = min((st + 3) & ~3, en);
    if (st + t < a0) {
        u32 v = bkt[st + t];
        float4 h = tab[v & 0x1FFFFu];
        int bin = (int)(v >> 17) * 3;
        atomicAdd(&acc[bin + 0], __float2int_rn(h.x * scale));
        atomicAdd(&acc[bin + 1], __float2int_rn(h.y * scale));
        atomicAdd(&acc[bin + 2], __float2int_rn(h.z * scale));
    }
    int vend = a0 + ((en - a0) & ~3);
    for (int i = a0 + t * 4; i < vend; i += P2_T * 4) {
        uint4 v = *(const uint4*)&bkt[i];
        float4 h0 = tab[v.x & 0x1FFFFu];
        float4 h1 = tab[v.y & 0x1FFFFu];
        float4 h2 = tab[v.z & 0x1FFFFu];
        float4 h3 = tab[v.w & 0x1FFFFu];
        int b0 = (int)(v.x >> 17) * 3, b1 = (int)(v.y >> 17) * 3;
        int b2 = (int)(v.z >> 17) * 3, b3 = (int)(v.w >> 17) * 3;
        atomicAdd(&acc[b0 + 0], __float2int_rn(h0.x * scale));
        atomicAdd(&acc[b0 + 1], __float2int_rn(h0.y * scale));
        atomicAdd(&acc[b0 + 2], __float2int_rn(h0.z * scale));
        atomicAdd(&acc[b1 + 0], __float2int_rn(h1.x * scale));
        atomicAdd(&acc[b1 + 1], __float2int_rn(h1.y * scale));
        atomicAdd(&acc[b1 + 2], __float2int_rn(h1.z * scale));
        atomicAdd(&acc[b2 + 0], __float2int_rn(h2.x * scale));
        atomicAdd(&acc[b2 + 1], __float2int_rn(h2.y * scale));
        atomicAdd(&acc[b2 + 2], __float2int_rn(h2.z * scale));
        atomicAdd(&acc[b3 + 0], __float2int_rn(h3.x * scale));
        atomicAdd(&acc[b3 + 1], __float2int_rn(h3.y * scale));
        atomicAdd(&acc[b3 + 2], __float2int_rn(h3.z * scale));
    }
    if (vend + t < en) {
        u32 v = bkt[vend + t];
        float4 h = tab[v & 0x1FFFFu];
        int bin = (int)(v >> 17) * 3;
        atomicAdd(&acc[bin + 0], __float2int_rn(h.x * scale));
        atomicAdd(&acc[bin + 1], __float2int_rn(h.y * scale));
        atomicAdd(&acc[bin + 2], __float2int_rn(h.z * scale));
    }
    __syncthreads();
    float* p = pacc + (size_t)blk * 768;
    p[t]       = (float)acc[t * 3 + 0] * inv_scale;
    p[t + 256] = (float)acc[t * 3 + 1] * inv_scale;
    p[t + 512] = (float)acc[t * 3 + 2] * inv_scale;
}

// ====== fin1: combine partials + self, chain @W1->leaky->@W2, *dinv ========
__global__ void k_fin1(const float* __restrict__ pacc, const float* __restrict__ dinv,
                       const float4* __restrict__ hd0,
                       const float* __restrict__ W1, const float* __restrict__ b1,
                       const float* __restrict__ W2,
                       float4* __restrict__ hd2, int nN) {
    int d = blockIdx.x * blockDim.x + threadIdx.x;
    if (d >= nN) return;
    int b = d >> 8, q = d & 255;
    float s0 = 0.f, s1 = 0.f, s2 = 0.f;
#pragma unroll
    for (int s = 0; s < ASPLIT; ++s) {
        const float* p = pacc + (size_t)(b * ASPLIT + s) * 768;
        s0 += p[q]; s1 += p[q + 256]; s2 += p[q + 512];
    }
    float di = dinv[d];
    float4 self = hd0[d];
    float a0 = di * (s0 + self.x);
    float a1 = di * (s1 + self.y);
    float a2 = di * (s2 + self.z);
    float o0 = 0.f, o1 = 0.f, o2 = 0.f;
#pragma unroll
    for (int k = 0; k < 16; ++k) {
        float p = leaky(a0 * W1[k] + a1 * W1[16 + k] + a2 * W1[32 + k] + b1[k]);
        o0 += p * W2[k * 3 + 0];
        o1 += p * W2[k * 3 + 1];
        o2 += p * W2[k * 3 + 2];
    }
    hd2[d] = make_float4(o0 * di, o1 * di, o2 * di, 0.f);
}

// ====== fin2 ===============================================================
__global__ void k_fin2(const float* __restrict__ pacc, const float* __restrict__ dinv,
                       const float4* __restrict__ hd2, const float* __restrict__ b2,
                       float4* __restrict__ h2, int nN) {
    int d = blockIdx.x * blockDim.x + threadIdx.x;
    if (d >= nN) return;
    int b = d >> 8, q = d & 255;
    float s0 = 0.f, s1 = 0.f, s2 = 0.f;
#pragma unroll
    for (int s = 0; s < ASPLIT; ++s) {
        const float* p = pacc + (size_t)(b * ASPLIT + s) * 768;
        s0 += p[q]; s1 += p[q + 256]; s2 += p[q + 512];
    }
    float di = dinv[d];
    float4 self = hd2[d];
    h2[d] = make_float4(leaky(di * (s0 + self.x) + b2[0]),
                        leaky(di * (s1 + self.y) + b2[1]),
                        leaky(di * (s2 + self.z) + b2[2]), 0.f);
}

// ================= per-match MLP: 4 matches per thread =====================
__global__ __launch_bounds__(256) void k_mlp4v(
        const int* __restrict__ home, const int* __restrict__ away,
        const float4* __restrict__ h2,
        const float* __restrict__ lw1, const float* __restrict__ lb1,
        const float* __restrict__ lw2, const float* __restrict__ lb2,
        const float* __restrict__ lw3, const float* __restrict__ lb3,
        float* __restrict__ out, int nM) {
    __shared__ float s[235];
    int t = threadIdx.x;
    if (t < 96)       s[t] = lw1[t];
    else if (t < 112) s[t] = lb1[t - 96];
    else if (t < 208) s[t] = lw2[t - 112];
    else if (t < 214) s[t] = lb2[t - 208];
    else if (t < 232) s[t] = lw3[t - 214];
    else if (t < 235) s[t] = lb3[t - 232];
    __syncthreads();
    const float* sw1 = s;        const float* sb1 = s + 96;
    const float* sw2 = s + 112;  const float* sb2 = s + 208;
    const float* sw3 = s + 214;  const float* sb3 = s + 232;

    int i = blockIdx.x * blockDim.x + threadIdx.x;   // quad index
    int m0 = i * 4;
    if (m0 >= nM) return;
    float res[12];
    int nq = min(4, nM - m0);
    int hidx[4], aidx[4];
    if (nq == 4) {
        int4 hv = *(const int4*)&home[m0];
        int4 av = *(const int4*)&away[m0];
        hidx[0] = hv.x; hidx[1] = hv.y; hidx[2] = hv.z; hidx[3] = hv.w;
        aidx[0] = av.x; aidx[1] = av.y; aidx[2] = av.z; aidx[3] = av.w;
    } else {
        for (int j = 0; j < nq; ++j) { hidx[j] = home[m0 + j]; aidx[j] = away[m0 + j]; }
    }
    for (int j = 0; j < nq; ++j) {
        float4 zh = h2[hidx[j]];
        float4 za = h2[aidx[j]];
        float z[6] = {zh.x, zh.y, zh.z, za.x, za.y, za.z};
        float t1[16];
#pragma unroll
        for (int k = 0; k < 16; ++k) {
            float p = sb1[k];
#pragma unroll
            for (int q = 0; q < 6; ++q) p += z[q] * sw1[q * 16 + k];
            t1[k] = leaky(p);
        }
        float t2[6];
#pragma unroll
        for (int k = 0; k < 6; ++k) {
            float p = sb2[k];
#pragma unroll
            for (int q = 0; q < 16; ++q) p += t1[q] * sw2[q * 6 + k];
            t2[k] = leaky(p);
        }
#pragma unroll
        for (int k = 0; k < 3; ++k) {
            float p = sb3[k];
#pragma unroll
            for (int q = 0; q < 6; ++q) p += t2[q] * sw3[q * 3 + k];
            res[j * 3 + k] = leaky(p);
        }
    }
    if (nq == 4) {
        float4* o4 = (float4*)&out[m0 * 3];
        o4[0] = make_float4(res[0], res[1], res[2], res[3]);
        o4[1] = make_float4(res[4], res[5], res[6], res[7]);
        o4[2] = make_float4(res[8], res[9], res[10], res[11]);
    } else {
        for (int j = 0; j < nq * 3; ++j) out[m0 * 3 + j] = res[j];
    }
}

// ================= fallback: atomic CSR build ===============
__global__ void k_hist(const int* __restrict__ dst, int* __restrict__ cnt, int nE) {
    int e = blockIdx.x * blockDim.x + threadIdx.x;
    if (e < nE) atomicAdd(&cnt[dst[e]], 1);
}
__global__ void k_prep(const int* __restrict__ off, const int* __restrict__ cnt,
                       float* __restrict__ dinv, int* __restrict__ cur, int nN) {
    int i = blockIdx.x * blockDim.x + threadIdx.x;
    if (i >= nN) return;
    dinv[i] = rsqrtf((float)cnt[i] + 1.0f);
    cur[i] = off[i];
}
__global__ void k_hd0(const int* __restrict__ x, const float* __restrict__ emb,
                      const float* __restrict__ dinv, float4* __restrict__ hd0, int nN) {
    int i = blockIdx.x * blockDim.x + threadIdx.x;
    if (i >= nN) return;
    float di = dinv[i];
    int xi = x[i] * 3;
    hd0[i] = make_float4(emb[xi] * di, emb[xi + 1] * di, emb[xi + 2] * di, 0.0f);
}
__global__ void k_place(const int* __restrict__ src, const int* __restrict__ dst,
                        int* __restrict__ cur, int* __restrict__ csr, int nE) {
    int e = blockIdx.x * blockDim.x + threadIdx.x;
    if (e >= nE) return;
    int p = atomicAdd(&cur[dst[e]], 1);
    csr[p] = src[e];
}
__global__ void k_gather1w(const int* __restrict__ off, const int* __restrict__ csr,
                           const float4* __restrict__ hd0, const float* __restrict__ dinv,
                           const float* __restrict__ W1, const float* __restrict__ b1,
                           const float* __restrict__ W2,
                           float4* __restrict__ hd2, int nN) {
    int g = blockIdx.x * blockDim.x + threadIdx.x;
    int d = g >> 6, lane = threadIdx.x & 63;
    if (d >= nN) return;
    int e0 = off[d], e1 = off[d + 1];
    float sx = 0.f, sy = 0.f, sz = 0.f;
    for (int e = e0 + lane; e < e1; e += 64) {
        float4 v = hd0[csr[e]];
        sx += v.x; sy += v.y; sz += v.z;
    }
    for (int o = 32; o; o >>= 1) {
        sx += __shfl_down(sx, o);
        sy += __shfl_down(sy, o);
        sz += __shfl_down(sz, o);
    }
    if (lane == 0) {
        float di = dinv[d];
        float4 self = hd0[d];
        float a0 = di * (sx + self.x);
        float a1 = di * (sy + self.y);
        float a2 = di * (sz + self.z);
        float o0 = 0.f, o1 = 0.f, o2 = 0.f;
#pragma unroll
        for (int k = 0; k < 16; ++k) {
            float p = leaky(a0 * W1[k] + a1 * W1[16 + k] + a2 * W1[32 + k] + b1[k]);
            o0 += p * W2[k * 3 + 0];
            o1 += p * W2[k * 3 + 1];
            o2 += p * W2[k * 3 + 2];
        }
        hd2[d] = make_float4(o0 * di, o1 * di, o2 * di, 0.0f);
    }
}
__global__ void k_gather2(const int* __restrict__ off, const int* __restrict__ csr,
                          const float4* __restrict__ hd2, const float* __restrict__ dinv,
                          const float* __restrict__ b2,
                          float4* __restrict__ h2, int nN) {
    int g = blockIdx.x * blockDim.x + threadIdx.x;
    int d = g >> 4, lane = threadIdx.x & 15;
    if (d >= nN) return;
    int e0 = off[d], e1 = off[d + 1];
    float s0 = 0.f, s1 = 0.f, s2 = 0.f;
    for (int e = e0 + lane; e < e1; e += 16) {
        float4 v = hd2[csr[e]];
        s0 += v.x; s1 += v.y; s2 += v.z;
    }
    for (int o = 8; o; o >>= 1) {
        s0 += __shfl_down(s0, o, 16);
        s1 += __shfl_down(s1, o, 16);
        s2 += __shfl_down(s2, o, 16);
    }
    if (lane == 0) {
        float di = dinv[d];
        float4 self = hd2[d];
        h2[d] = make_float4(leaky(di * (s0 + self.x) + b2[0]),
                            leaky(di * (s1 + self.y) + b2[1]),
                            leaky(di * (s2 + self.z) + b2[2]), 0.f);
    }
}

// ================= launch =================
extern "C" void kernel_launch(void* const* d_in, const int* in_sizes, int n_in,
                              void* d_out, int out_size, void* d_ws, size_t ws_size,
                              hipStream_t stream) {
    const int*   x    = (const int*)d_in[0];
    const int*   ei   = (const int*)d_in[1];
    const int*   home = (const int*)d_in[2];
    const int*   away = (const int*)d_in[3];
    const float* emb  = (const float*)d_in[4];
    const float* W1   = (const float*)d_in[5];
    const float* b1   = (const float*)d_in[6];
    const float* W2   = (const float*)d_in[7];
    const float* b2   = (const float*)d_in[8];
    const float* lw1  = (const float*)d_in[9];
    const float* lb1  = (const float*)d_in[10];
    const float* lw2  = (const float*)d_in[11];
    const float* lb2  = (const float*)d_in[12];
    const float* lw3  = (const float*)d_in[13];
    const float* lb3  = (const float*)d_in[14];
    float* out = (float*)d_out;

    const int nN = in_sizes[0];       // 100000
    const int nE = in_sizes[1] / 2;   // 5M
    const int nM = in_sizes[2];       // 1M
    const int* src = ei;
    const int* dst = ei + nE;
    const int B = 256;

    const int nb1 = (nE + P1_CHUNK - 1) / P1_CHUNK;
    const int ghN = NBK * nb1;
    const int nbs = (ghN + SBLK - 1) / SBLK;
    const size_t paccN = (size_t)NBK * ASPLIT * 768;   // floats

    size_t need = (size_t)3 * nN * 16 + (size_t)nE * 4 + (size_t)(ghN + 1) * 4 +
                  paccN * 4 + (size_t)nN * 4 + (size_t)(nbs + 8) * 4;

    if (nN <= NBK * 256 && ws_size >= need && nbs <= SBLK) {
        char* w = (char*)d_ws;
        float4* hd0 = (float4*)w;                 w += (size_t)nN * 16;
        float4* hd2 = (float4*)w;                 w += (size_t)nN * 16;
        float4* h2  = (float4*)w;                 w += (size_t)nN * 16;
        u32* bkt  = (u32*)w;                      w += (size_t)nE * 4;
        float* pacc = (float*)w;                  w += paccN * 4;
        int* gh   = (int*)w;                      w += (size_t)(ghN + 1) * 4;
        float* dinv = (float*)w;                  w += (size_t)nN * 4;
        int* bsum = (int*)w;

        k_p1hist<<<nb1, P1_T, 0, stream>>>(dst, gh, nE, nb1);
        g_scanA<<<nbs, SBLK, 0, stream>>>(gh, gh, bsum, ghN);
        g_scanB<<<1, SBLK, 0, stream>>>(bsum, nbs);
        k_p1scatter<<<nb1, P1_T, 0, stream>>>(src, dst, gh, bsum, bkt, nE, nb1, ghN);
        k_cnt1<<<NBK, P2_T, 0, stream>>>(bkt, gh, bsum, x, emb, dinv, hd0,
                                         nE, nb1, ghN, nN);
        k_aggI<<<NBK * ASPLIT, P2_T, 0, stream>>>(bkt, gh, bsum, hd0, pacc,
                                                  nE, nb1, ghN, S1F, 1.0f / S1F);
        k_fin1<<<(nN + B - 1) / B, B, 0, stream>>>(pacc, dinv, hd0, W1, b1, W2,
                                                   hd2, nN);
        k_aggI<<<NBK * ASPLIT, P2_T, 0, stream>>>(bkt, gh, bsum, hd2, pacc,
                                                  nE, nb1, ghN, S2F, 1.0f / S2F);
        k_fin2<<<(nN + B - 1) / B, B, 0, stream>>>(pacc, dinv, hd2, b2, h2, nN);
        int nQuads = (nM + 3) / 4;
        k_mlp4v<<<(nQuads + B - 1) / B, B, 0, stream>>>(home, away, h2,
                                                        lw1, lb1, lw2, lb2, lw3, lb3,
                                                        out, nM);
    } else {
        // fallback: atomic CSR build
        char* w = (char*)d_ws;
        float4* hd0 = (float4*)w;                 w += (size_t)nN * 16;
        float4* hd2 = (float4*)w;                 w += (size_t)nN * 16;
        float4* h2  = (float4*)w;                 w += (size_t)nN * 16;
        int* csr  = (int*)w;                      w += (size_t)nE * 4;
        int* cnt  = (int*)w;                      w += (size_t)(nN + 1) * 4;
        int* off  = (int*)w;                      w += (size_t)(nN + 1) * 4;
        int* cur  = (int*)w;                      w += (size_t)nN * 4;
        float* dinv = (float*)w;                  w += (size_t)nN * 4;
        int* bsum = (int*)w;

        const int nTot = nN + 1;
        const int nbScan = (nTot + SBLK - 1) / SBLK;

        hipMemsetAsync(cnt, 0, (size_t)nTot * sizeof(int), stream);
        k_hist<<<(nE + B - 1) / B, B, 0, stream>>>(dst, cnt, nE);
        g_scanA<<<nbScan, SBLK, 0, stream>>>(cnt, off, bsum, nTot);
        g_scanB<<<1, SBLK, 0, stream>>>(bsum, nbScan);
        g_scanC<<<(nTot + B - 1) / B, B, 0, stream>>>(off, bsum, nTot - 1, nE);
        k_prep<<<(nN + B - 1) / B, B, 0, stream>>>(off, cnt, dinv, cur, nN);
        k_hd0<<<(nN + B - 1) / B, B, 0, stream>>>(x, emb, dinv, hd0, nN);
        k_place<<<(nE + B - 1) / B, B, 0, stream>>>(src, dst, cur, csr, nE);
        k_gather1w<<<((size_t)nN * 64 + B - 1) / B, B, 0, stream>>>(off, csr, hd0, dinv,
                                                                    W1, b1, W2, hd2, nN);
        k_gather2<<<((size_t)nN * 16 + B - 1) / B, B, 0, stream>>>(off, csr, hd2,
                                                                   dinv, b2, h2, nN);
        int nQuads = (nM + 3) / 4;
        k_mlp4v<<<(nQuads + B - 1) / B, B, 0, stream>>>(home, away, h2,
                                                        lw1, lb1, lw2, lb2, lw3, lb3,
                                                        out, nM);
    }
}